// Round 1
// 2096.270 us; speedup vs baseline: 1.2869x; 1.2869x over previous
//
#include <hip/hip_runtime.h>
#include <hip/hip_bf16.h>

#define BB 32
#define NN 520
#define MM 520
#define EE 128
#define HH 8
#define DKK 16
#define FFH_ 512
#define NL_ 6
#define DEPOT_ 20
#define LL 40

typedef short short8 __attribute__((ext_vector_type(8)));
typedef short bshort4 __attribute__((ext_vector_type(4)));
typedef float floatx4 __attribute__((ext_vector_type(4)));

__device__ __forceinline__ unsigned short f2b(float x) {
    unsigned int u = __float_as_uint(x);
    return (unsigned short)((u + 0x7fffu + ((u >> 16) & 1u)) >> 16);
}
__device__ __forceinline__ float b2f_(unsigned short h) {
    return __uint_as_float(((unsigned int)h) << 16);
}

// ---------------- embedding: depot/customer linear ----------------
__global__ __launch_bounds__(256) void embed_k(
    const float* __restrict__ dep, const float* __restrict__ cus,
    const float* __restrict__ Wd, const float* __restrict__ bd,
    const float* __restrict__ Wc3, const float* __restrict__ bc,
    float* __restrict__ x)
{
    int idx = blockIdx.x * 256 + threadIdx.x;   // < B*N*E = 2129920
    int e = idx & 127;
    int bn = idx >> 7;
    int n = bn % NN;
    int b = bn / NN;
    float a;
    if (n < DEPOT_) {
        a = bd[e];
        const float* f = dep + ((size_t)(b * DEPOT_ + n)) * 4;
        #pragma unroll
        for (int j = 0; j < 4; j++) a += f[j] * Wd[e * 4 + j];
    } else {
        a = bc[e];
        const float* f = cus + ((size_t)(b * 500 + (n - DEPOT_))) * 3;
        #pragma unroll
        for (int j = 0; j < 3; j++) a += f[j] * Wc3[e * 3 + j];
    }
    x[idx] = a;
}

// ---------------- bf16x3 MFMA GEMM: C[m,n] = sum_k A[m,k]*W[n,k] + bias[n] ----------------
// Block tile 128(m) x 64(n), BK=32, 4 waves. Each value split a = hi(bf16) + lo(bf16);
// A*B ~= AhBh + AhBl + AlBh (error ~2^-17 relative, fp32-equivalent here).
// Frag layouts (verified m89/m120): A/B idx=lane&15, k=(lane>>4)*8+j; C col=lane&15,
// row=(lane>>4)*4+reg. Rows padded to 40 shorts (80B) -> 16B-aligned, 2-way banks (free).
#define AP 40
__global__ __launch_bounds__(256) void gemm_mfma_k(
    const float* __restrict__ A, int lda,
    const float* __restrict__ W, int ldw,
    const float* __restrict__ bias,
    float* __restrict__ C, int ldc,
    int K, int relu)
{
    __shared__ __align__(16) unsigned short Ah[128][AP];
    __shared__ __align__(16) unsigned short Al[128][AP];
    __shared__ __align__(16) unsigned short Bh[64][AP];
    __shared__ __align__(16) unsigned short Bl[64][AP];

    int t = threadIdx.x;
    int w = t >> 6, lane = t & 63;
    int frow = lane & 15, fq = lane >> 4;
    int n0 = blockIdx.x * 64, m0 = blockIdx.y * 128;

    int arow = t & 127, ahalf = (t >> 7) * 16;   // A: 128 rows x 32 cols, 16 floats/thread
    int brow = t & 63,  bq    = (t >> 6) * 8;    // B: 64 rows x 32 cols, 8 floats/thread

    floatx4 acc[2][4];
    #pragma unroll
    for (int i = 0; i < 2; i++)
        #pragma unroll
        for (int j = 0; j < 4; j++)
            acc[i][j] = (floatx4){0.0f, 0.0f, 0.0f, 0.0f};

    for (int k0 = 0; k0 < K; k0 += 32) {
        // ---- stage A (hi/lo bf16) ----
        {
            const float* Ap = A + (size_t)(m0 + arow) * lda + k0 + ahalf;
            float vr[16];
            #pragma unroll
            for (int j = 0; j < 4; j++) {
                float4 v = ((const float4*)Ap)[j];
                vr[j * 4 + 0] = v.x; vr[j * 4 + 1] = v.y;
                vr[j * 4 + 2] = v.z; vr[j * 4 + 3] = v.w;
            }
            short8 hv0, hv1, lv0, lv1;
            #pragma unroll
            for (int j = 0; j < 8; j++) {
                unsigned short h = f2b(vr[j]);
                hv0[j] = (short)h;
                lv0[j] = (short)f2b(vr[j] - b2f_(h));
            }
            #pragma unroll
            for (int j = 0; j < 8; j++) {
                unsigned short h = f2b(vr[8 + j]);
                hv1[j] = (short)h;
                lv1[j] = (short)f2b(vr[8 + j] - b2f_(h));
            }
            *((short8*)&Ah[arow][ahalf])     = hv0;
            *((short8*)&Ah[arow][ahalf + 8]) = hv1;
            *((short8*)&Al[arow][ahalf])     = lv0;
            *((short8*)&Al[arow][ahalf + 8]) = lv1;
        }
        // ---- stage B (hi/lo bf16) ----
        {
            const float* Wp = W + (size_t)(n0 + brow) * ldw + k0 + bq;
            float4 v0 = ((const float4*)Wp)[0];
            float4 v1 = ((const float4*)Wp)[1];
            float wr[8] = {v0.x, v0.y, v0.z, v0.w, v1.x, v1.y, v1.z, v1.w};
            short8 hv, lv;
            #pragma unroll
            for (int j = 0; j < 8; j++) {
                unsigned short h = f2b(wr[j]);
                hv[j] = (short)h;
                lv[j] = (short)f2b(wr[j] - b2f_(h));
            }
            *((short8*)&Bh[brow][bq]) = hv;
            *((short8*)&Bl[brow][bq]) = lv;
        }
        __syncthreads();

        // ---- MFMA: 2 m-tiles x 4 n-tiles x 3 passes ----
        short8 ah0 = *((const short8*)&Ah[w * 32 + frow][fq * 8]);
        short8 ah1 = *((const short8*)&Ah[w * 32 + 16 + frow][fq * 8]);
        short8 al0 = *((const short8*)&Al[w * 32 + frow][fq * 8]);
        short8 al1 = *((const short8*)&Al[w * 32 + 16 + frow][fq * 8]);
        #pragma unroll
        for (int nt = 0; nt < 4; nt++) {
            short8 bh = *((const short8*)&Bh[nt * 16 + frow][fq * 8]);
            short8 bl = *((const short8*)&Bl[nt * 16 + frow][fq * 8]);
            acc[0][nt] = __builtin_amdgcn_mfma_f32_16x16x32_bf16(ah0, bh, acc[0][nt], 0, 0, 0);
            acc[1][nt] = __builtin_amdgcn_mfma_f32_16x16x32_bf16(ah1, bh, acc[1][nt], 0, 0, 0);
            acc[0][nt] = __builtin_amdgcn_mfma_f32_16x16x32_bf16(ah0, bl, acc[0][nt], 0, 0, 0);
            acc[1][nt] = __builtin_amdgcn_mfma_f32_16x16x32_bf16(ah1, bl, acc[1][nt], 0, 0, 0);
            acc[0][nt] = __builtin_amdgcn_mfma_f32_16x16x32_bf16(al0, bh, acc[0][nt], 0, 0, 0);
            acc[1][nt] = __builtin_amdgcn_mfma_f32_16x16x32_bf16(al1, bh, acc[1][nt], 0, 0, 0);
        }
        __syncthreads();
    }

    // ---- epilogue ----
    #pragma unroll
    for (int nt = 0; nt < 4; nt++) {
        int col = n0 + nt * 16 + frow;
        float bv = bias ? bias[col] : 0.0f;
        #pragma unroll
        for (int mt = 0; mt < 2; mt++) {
            int rbase = m0 + w * 32 + mt * 16 + fq * 4;
            #pragma unroll
            for (int r = 0; r < 4; r++) {
                float v = acc[mt][nt][r] + bv;
                if (relu) v = fmaxf(v, 0.0f);
                C[(size_t)(rbase + r) * ldc + col] = v;
            }
        }
    }
}

// ---------------- score GEMM (NT) with tanh epilogue (fp32) ----------------
#define GT 64
#define GK 32
#define GP 36
__global__ __launch_bounds__(256) void sgemm_k(
    const float* __restrict__ A,    // score [B*520][128]
    const float* __restrict__ Enc,  // [B*520][128]
    float* __restrict__ C)          // [B][520][520]
{
    __shared__ float As[GT][GP];
    __shared__ float Ws[GT][GP];
    int t = threadIdx.x;
    int tx = t & 15, ty = t >> 4;
    int b = blockIdx.z;
    int m0 = blockIdx.y * GT, n0 = blockIdx.x * GT;
    int lr = t >> 2, lc = (t & 3) * 8;
    int mr = m0 + lr; if (mr >= NN) mr = NN - 1;
    int nr = n0 + lr; if (nr >= NN) nr = NN - 1;
    float acc[4][4];
    #pragma unroll
    for (int i = 0; i < 4; i++)
        #pragma unroll
        for (int j = 0; j < 4; j++) acc[i][j] = 0.0f;

    for (int k0 = 0; k0 < EE; k0 += GK) {
        const float* Ap = A + ((size_t)(b * NN + mr)) * EE + k0 + lc;
        const float* Wp = Enc + ((size_t)(b * NN + nr)) * EE + k0 + lc;
        float4 av0 = *((const float4*)Ap), av1 = *((const float4*)(Ap + 4));
        float4 wv0 = *((const float4*)Wp), wv1 = *((const float4*)(Wp + 4));
        *((float4*)&As[lr][lc]) = av0; *((float4*)&As[lr][lc + 4]) = av1;
        *((float4*)&Ws[lr][lc]) = wv0; *((float4*)&Ws[lr][lc + 4]) = wv1;
        __syncthreads();
        #pragma unroll
        for (int kk = 0; kk < GK; kk += 2) {
            float2 a0 = *((const float2*)&As[ty][kk]);
            float2 a1 = *((const float2*)&As[ty + 16][kk]);
            float2 a2 = *((const float2*)&As[ty + 32][kk]);
            float2 a3 = *((const float2*)&As[ty + 48][kk]);
            float2 w0 = *((const float2*)&Ws[tx][kk]);
            float2 w1 = *((const float2*)&Ws[tx + 16][kk]);
            float2 w2 = *((const float2*)&Ws[tx + 32][kk]);
            float2 w3 = *((const float2*)&Ws[tx + 48][kk]);
            acc[0][0] += a0.x * w0.x + a0.y * w0.y;
            acc[0][1] += a0.x * w1.x + a0.y * w1.y;
            acc[0][2] += a0.x * w2.x + a0.y * w2.y;
            acc[0][3] += a0.x * w3.x + a0.y * w3.y;
            acc[1][0] += a1.x * w0.x + a1.y * w0.y;
            acc[1][1] += a1.x * w1.x + a1.y * w1.y;
            acc[1][2] += a1.x * w2.x + a1.y * w2.y;
            acc[1][3] += a1.x * w3.x + a1.y * w3.y;
            acc[2][0] += a2.x * w0.x + a2.y * w0.y;
            acc[2][1] += a2.x * w1.x + a2.y * w1.y;
            acc[2][2] += a2.x * w2.x + a2.y * w2.y;
            acc[2][3] += a2.x * w3.x + a2.y * w3.y;
            acc[3][0] += a3.x * w0.x + a3.y * w0.y;
            acc[3][1] += a3.x * w1.x + a3.y * w1.y;
            acc[3][2] += a3.x * w2.x + a3.y * w2.y;
            acc[3][3] += a3.x * w3.x + a3.y * w3.y;
        }
        __syncthreads();
    }
    #pragma unroll
    for (int i = 0; i < 4; i++) {
        int m = m0 + ty + 16 * i;
        if (m >= NN) continue;
        #pragma unroll
        for (int j = 0; j < 4; j++) {
            int n = n0 + tx + 16 * j;
            if (n >= NN) continue;
            float v = 10.0f * tanhf(acc[i][j] * 0.088388347648318447f);
            C[((size_t)(b * NN + m)) * NN + n] = v;
        }
    }
}

// ---------------- row softmax: out = softmax(logits + mask) ----------------
__global__ __launch_bounds__(64) void smax_k(
    const float* __restrict__ L, const float* __restrict__ mask,
    float* __restrict__ out)
{
    int bm = blockIdx.x;
    int t = threadIdx.x;
    const float* Lr = L + (size_t)bm * NN;
    const float* Mr = mask + (size_t)bm * NN;
    float v[9];
    float mx = -1e30f;
    #pragma unroll
    for (int i = 0; i < 9; i++) {
        int idx = t + i * 64;
        if (idx < NN) { v[i] = Lr[idx] + Mr[idx]; mx = fmaxf(mx, v[i]); }
        else v[i] = -1e30f;
    }
    #pragma unroll
    for (int o = 32; o > 0; o >>= 1) mx = fmaxf(mx, __shfl_xor(mx, o));
    float s = 0.0f;
    #pragma unroll
    for (int i = 0; i < 9; i++) {
        int idx = t + i * 64;
        float e = (idx < NN) ? expf(v[i] - mx) : 0.0f;
        v[i] = e; s += e;
    }
    #pragma unroll
    for (int o = 32; o > 0; o >>= 1) s += __shfl_xor(s, o);
    float inv = 1.0f / s;
    #pragma unroll
    for (int i = 0; i < 9; i++) {
        int idx = t + i * 64;
        if (idx < NN) out[(size_t)bm * NN + idx] = v[i] * inv;
    }
}

// ---------------- MFMA flash attention (bf16x3, fp32-equivalent) ----------------
// One block = 4 waves, 64 q-rows, one (head, batch). DK=16 -> mfma_f32_16x16x16_bf16.
// Swapped QK^T: S^T = mfma(A=K, B=Q) puts, per lane, q = lane&15 and
// kc = 16*s + 4*(lane>>4) + r  (s = 16-col sub-tile, r = C reg).
//  - row-softmax = 16 in-lane values + shfl_xor(16,32)   (no LDS, no divergence)
//  - exp'd values ARE the PV A-frag (A: row=lane&15, k=4*(lane>>4)+j)  -> no P transpose
// K staged in LDS hi/lo bf16, row stride 20 shorts (40B): ds_read_b64 conflict-free.
// V staged transposed [d][kc], row stride 72 shorts (144B): ds_read_b64 conflict-free.
// 3-pass hi/lo split on both GEMMs keeps accuracy fp32-equivalent (~2^-16 rel).
#define ATQ 64
#define ATK 64
__global__ __launch_bounds__(256) void fmha16_k(
    const float* __restrict__ Q, const float* __restrict__ K,
    const float* __restrict__ V, const float* __restrict__ mask,
    float* __restrict__ O, int Nq, int Nk)
{
    __shared__ __align__(16) unsigned short Khi[ATK][20];
    __shared__ __align__(16) unsigned short Klo[ATK][20];
    __shared__ __align__(16) unsigned short Vhi[16][72];
    __shared__ __align__(16) unsigned short Vlo[16][72];

    int qt = blockIdx.x, h = blockIdx.y, b = blockIdx.z;
    int t = threadIdx.x;
    int w = t >> 6, lane = t & 63;
    int r16 = lane & 15, g = lane >> 4;

    // ---- Q fragment (hi/lo bf16): Q[q = qbase+r16][dk = 4g+j] ----
    int qbase = qt * ATQ + w * 16;
    int qg = qbase + r16;
    int qc = qg < Nq ? qg : Nq - 1;
    bshort4 qh, ql;
    {
        float4 qv = *((const float4*)(Q + ((size_t)(b * Nq + qc)) * EE + h * 16 + 4 * g));
        float qa[4] = {qv.x, qv.y, qv.z, qv.w};
        #pragma unroll
        for (int j = 0; j < 4; j++) {
            unsigned short hh = f2b(qa[j]);
            qh[j] = (short)hh;
            ql[j] = (short)f2b(qa[j] - b2f_(hh));
        }
    }

    floatx4 o_acc = (floatx4){0.0f, 0.0f, 0.0f, 0.0f};
    float m_i = -1e30f, l_i = 0.0f;

    int skr = t >> 2;          // staging k-row 0..63
    int sc  = (t & 3) * 4;     // staging col 0/4/8/12

    const float* mrow = mask ? (mask + ((size_t)(b * Nq + qc)) * Nk) : nullptr;

    int nkt = (Nk + ATK - 1) / ATK;
    for (int kt = 0; kt < nkt; kt++) {
        int k0 = kt * ATK;
        __syncthreads();
        // ---- stage K (hi/lo) and V (transposed hi/lo) ----
        {
            int kr = k0 + skr;
            int krc = kr < Nk ? kr : Nk - 1;
            float4 kv = *((const float4*)(K + ((size_t)(b * Nk + krc)) * EE + h * 16 + sc));
            float4 vv = *((const float4*)(V + ((size_t)(b * Nk + krc)) * EE + h * 16 + sc));
            float ka[4] = {kv.x, kv.y, kv.z, kv.w};
            float va[4] = {vv.x, vv.y, vv.z, vv.w};
            bshort4 khv, klv;
            #pragma unroll
            for (int j = 0; j < 4; j++) {
                unsigned short hh = f2b(ka[j]);
                khv[j] = (short)hh;
                klv[j] = (short)f2b(ka[j] - b2f_(hh));
            }
            *((bshort4*)&Khi[skr][sc]) = khv;
            *((bshort4*)&Klo[skr][sc]) = klv;
            #pragma unroll
            for (int j = 0; j < 4; j++) {
                unsigned short hh = f2b(va[j]);
                Vhi[sc + j][skr] = hh;
                Vlo[sc + j][skr] = (unsigned short)f2b(va[j] - b2f_(hh));
            }
        }
        __syncthreads();

        // ---- S^T: 4 sub-tiles x 3 passes ----
        float p[4][4];
        #pragma unroll
        for (int s = 0; s < 4; s++) {
            bshort4 kh = *((const bshort4*)&Khi[s * 16 + r16][4 * g]);
            bshort4 kl = *((const bshort4*)&Klo[s * 16 + r16][4 * g]);
            floatx4 acc = (floatx4){0.0f, 0.0f, 0.0f, 0.0f};
            acc = __builtin_amdgcn_mfma_f32_16x16x16bf16_1k(kh, qh, acc, 0, 0, 0);
            acc = __builtin_amdgcn_mfma_f32_16x16x16bf16_1k(kh, ql, acc, 0, 0, 0);
            acc = __builtin_amdgcn_mfma_f32_16x16x16bf16_1k(kl, qh, acc, 0, 0, 0);
            #pragma unroll
            for (int r = 0; r < 4; r++) p[s][r] = acc[r];
        }

        // ---- scale + mask + bounds ----
        #pragma unroll
        for (int s = 0; s < 4; s++) {
            #pragma unroll
            for (int r = 0; r < 4; r++) {
                int kc = k0 + s * 16 + 4 * g + r;
                float v = p[s][r] * 0.25f;
                if (mrow && kc < Nk) v += mrow[kc];
                p[s][r] = (kc < Nk) ? v : -1e30f;
            }
        }

        // ---- online softmax (per q = lane&15) ----
        float tmax = -1e30f;
        #pragma unroll
        for (int s = 0; s < 4; s++)
            #pragma unroll
            for (int r = 0; r < 4; r++) tmax = fmaxf(tmax, p[s][r]);
        tmax = fmaxf(tmax, __shfl_xor(tmax, 16));
        tmax = fmaxf(tmax, __shfl_xor(tmax, 32));
        float m_new = fmaxf(m_i, tmax);
        float alpha = __expf(m_i - m_new);
        float lloc = 0.0f;
        #pragma unroll
        for (int s = 0; s < 4; s++) {
            #pragma unroll
            for (int r = 0; r < 4; r++) {
                float e = __expf(p[s][r] - m_new);
                p[s][r] = e; lloc += e;
            }
        }
        lloc += __shfl_xor(lloc, 16);
        lloc += __shfl_xor(lloc, 32);
        l_i = l_i * alpha + lloc;
        m_i = m_new;

        // ---- rescale O (O reg r holds q-row 4g+r; alpha lives at lane q) ----
        #pragma unroll
        for (int r = 0; r < 4; r++) {
            float ar = __shfl(alpha, 4 * g + r);
            o_acc[r] *= ar;
        }

        // ---- PV: p is already the A-frag; V frag from transposed LDS ----
        #pragma unroll
        for (int s = 0; s < 4; s++) {
            bshort4 ph, pl;
            #pragma unroll
            for (int r = 0; r < 4; r++) {
                unsigned short hh = f2b(p[s][r]);
                ph[r] = (short)hh;
                pl[r] = (short)f2b(p[s][r] - b2f_(hh));
            }
            bshort4 vh = *((const bshort4*)&Vhi[r16][s * 16 + 4 * g]);
            bshort4 vl = *((const bshort4*)&Vlo[r16][s * 16 + 4 * g]);
            o_acc = __builtin_amdgcn_mfma_f32_16x16x16bf16_1k(ph, vh, o_acc, 0, 0, 0);
            o_acc = __builtin_amdgcn_mfma_f32_16x16x16bf16_1k(ph, vl, o_acc, 0, 0, 0);
            o_acc = __builtin_amdgcn_mfma_f32_16x16x16bf16_1k(pl, vh, o_acc, 0, 0, 0);
        }
    }

    // ---- epilogue: O reg r is (q-row 4g+r, d = r16); l lives at lane q ----
    #pragma unroll
    for (int r = 0; r < 4; r++) {
        float lr = __shfl(l_i, 4 * g + r);
        int qrow = qbase + 4 * g + r;
        if (qrow < Nq)
            O[((size_t)(b * Nq + qrow)) * EE + h * 16 + r16] = o_acc[r] / lr;
    }
}

// ---------------- InstanceNorm over node axis ----------------
__global__ __launch_bounds__(64) void inorm_k(
    const float* __restrict__ X, const float* __restrict__ Y,
    const float* __restrict__ g, const float* __restrict__ bb,
    float* __restrict__ Out)
{
    int be = blockIdx.x;
    int b = be >> 7, e = be & 127;
    int t = threadIdx.x;
    float vals[9];
    float s = 0.0f, s2 = 0.0f;
    int c = 0;
    for (int n = t; n < NN; n += 64) {
        size_t off = ((size_t)(b * NN + n)) * EE + e;
        float v = X[off] + Y[off];
        vals[c++] = v; s += v; s2 += v * v;
    }
    #pragma unroll
    for (int o = 32; o > 0; o >>= 1) { s += __shfl_down(s, o); s2 += __shfl_down(s2, o); }
    s = __shfl(s, 0); s2 = __shfl(s2, 0);
    float mu = s * (1.0f / NN);
    float var = s2 * (1.0f / NN) - mu * mu;
    float inv = rsqrtf(var + 1e-5f);
    float gg = g[e], bv = bb[e];
    c = 0;
    for (int n = t; n < NN; n += 64) {
        size_t off = ((size_t)(b * NN + n)) * EE + e;
        Out[off] = (vals[c++] - mu) * inv * gg + bv;
    }
}

__global__ void zero_k(float* p, int n) {
    int i = blockIdx.x * 256 + threadIdx.x;
    if (i < n) p[i] = 0.0f;
}

__global__ __launch_bounds__(128) void encsum_k(const float* __restrict__ enc, float* __restrict__ esum) {
    int b = blockIdx.x, ch = blockIdx.y, t = threadIdx.x;
    float a = 0.0f;
    for (int i = 0; i < 65; i++) {
        int n = ch * 65 + i;
        a += enc[((size_t)(b * NN + n)) * EE + t];
    }
    atomicAdd(&esum[b * EE + t], a);
}

// mt[b,e] = sum_f (esum[b,f]/N) * Wr[e, 128+f]
__global__ __launch_bounds__(128) void meanterm_k(
    const float* __restrict__ esum, const float* __restrict__ Wr, float* __restrict__ mt)
{
    int b = blockIdx.x, t = threadIdx.x;
    __shared__ float em[128];
    em[t] = esum[b * EE + t] * (1.0f / NN);
    __syncthreads();
    const float* w = Wr + (size_t)t * 257 + 128;
    float a = 0.0f;
    for (int f = 0; f < 128; f++) a += em[f] * w[f];
    mt[b * EE + t] = a;
}

__global__ __launch_bounds__(128) void subtour_k(
    const float* __restrict__ enc, const int* __restrict__ subn,
    const int* __restrict__ subl, float* __restrict__ subm)
{
    int bm = blockIdx.x;
    int b = bm / MM;
    int t = threadIdx.x;
    int len = subl[bm];
    float acc = 0.0f; int cnt = 0;
    for (int l = 0; l < LL; l++) {
        int node = subn[(size_t)bm * LL + l];
        if (l < len && node >= DEPOT_) {
            acc += enc[((size_t)(b * NN + node)) * EE + t];
            cnt++;
        }
    }
    float cf = (float)(cnt < 1 ? 1 : cnt);
    subm[(size_t)bm * EE + t] = acc / cf;
}

__global__ __launch_bounds__(128) void decq_k(
    const float* __restrict__ enc, const float* __restrict__ subm,
    const float* __restrict__ mterm, const int* __restrict__ cur,
    const float* __restrict__ loadv, const int* __restrict__ sel,
    const float* __restrict__ Wl, const float* __restrict__ Wr,
    float* __restrict__ out)
{
    int bm = blockIdx.x;
    int b = bm / MM;
    int t = threadIdx.x;
    __shared__ float le[128], sm[128];
    int cn = cur[bm];
    le[t] = enc[((size_t)(b * NN + cn)) * EE + t];
    sm[t] = subm[(size_t)bm * EE + t];
    __syncthreads();
    int s2v = sel[(size_t)bm * 4 + 2];   // selected[:,:,-2]
    bool flag = (s2v >= DEPOT_) && (cn < DEPOT_);
    float q;
    if (flag) {
        const float* w = Wl + (size_t)t * 256;
        float a = 0.0f;
        for (int f = 0; f < 128; f++) a += le[f] * w[f];
        for (int f = 0; f < 128; f++) a += sm[f] * w[128 + f];
        q = a;
    } else {
        const float* w = Wr + (size_t)t * 257;
        float a = mterm[b * EE + t] + loadv[bm] * w[256];
        for (int f = 0; f < 128; f++) a += le[f] * w[f];
        q = a;
    }
    out[(size_t)bm * EE + t] = q;
}

extern "C" void kernel_launch(void* const* d_in, const int* in_sizes, int n_in,
                              void* d_out, int out_size, void* d_ws, size_t ws_size,
                              hipStream_t stream)
{
    const float* depot = (const float*)d_in[0];
    const float* cust  = (const float*)d_in[1];
    const float* mask  = (const float*)d_in[2];
    const float* loadv = (const float*)d_in[3];
    const int*  cur   = (const int*)d_in[4];
    const int*  subn  = (const int*)d_in[5];
    const int*  subl  = (const int*)d_in[6];
    const int*  sel   = (const int*)d_in[7];
    const float* Wdep  = (const float*)d_in[8];
    const float* bdep  = (const float*)d_in[9];
    const float* Wcus  = (const float*)d_in[10];
    const float* bcus  = (const float*)d_in[11];
    const float* Wq    = (const float*)d_in[12];
    const float* Wk    = (const float*)d_in[13];
    const float* Wv    = (const float*)d_in[14];
    const float* Wc    = (const float*)d_in[15];
    const float* Wcb   = (const float*)d_in[16];
    const float* n1g   = (const float*)d_in[17];
    const float* n1b   = (const float*)d_in[18];
    const float* fW1   = (const float*)d_in[19];
    const float* fb1   = (const float*)d_in[20];
    const float* fW2   = (const float*)d_in[21];
    const float* fb2   = (const float*)d_in[22];
    const float* n2g   = (const float*)d_in[23];
    const float* n2b   = (const float*)d_in[24];
    const float* Wql   = (const float*)d_in[25];
    const float* Wqr   = (const float*)d_in[26];
    const float* dWk   = (const float*)d_in[27];
    const float* dWv   = (const float*)d_in[28];
    const float* dWc   = (const float*)d_in[29];
    const float* dWcb  = (const float*)d_in[30];

    const size_t SZ = (size_t)BB * NN * EE;           // 2,129,920
    float* f0 = (float*)d_ws;       // x / encoded
    float* f1 = f0 + SZ;            // q / k_d / logits (spans f1..f5)
    float* f2 = f1 + SZ;            // k / v_d
    float* f3 = f2 + SZ;            // v / encsum + meanterm
    float* f4 = f3 + SZ;            // mh,ff2 out / sub_mean, dec attn
    float* f5 = f4 + SZ;            // x1 / final_q
    float* big = f5 + SZ;           // ffh (B*N*FFH) / dec score

    dim3 g4(EE / 64, (BB * NN) / 128);     // (2, 130)
    dim3 g16(FFH_ / 64, (BB * NN) / 128);  // (8, 130)
    dim3 gmha((NN + ATQ - 1) / ATQ, HH, BB);  // (9, 8, 32)
    dim3 gsc((NN + GT - 1) / GT, (NN + GT - 1) / GT, BB);  // (9, 9, 32)

    embed_k<<<(BB * NN * EE) / 256, 256, 0, stream>>>(depot, cust, Wdep, bdep, Wcus, bcus, f0);

    for (int i = 0; i < NL_; i++) {
        const float* wq = Wq + (size_t)i * EE * EE;
        const float* wk = Wk + (size_t)i * EE * EE;
        const float* wv = Wv + (size_t)i * EE * EE;
        const float* wc = Wc + (size_t)i * EE * EE;
        gemm_mfma_k<<<g4, 256, 0, stream>>>(f0, EE, wq, EE, nullptr, f1, EE, EE, 0);
        gemm_mfma_k<<<g4, 256, 0, stream>>>(f0, EE, wk, EE, nullptr, f2, EE, EE, 0);
        gemm_mfma_k<<<g4, 256, 0, stream>>>(f0, EE, wv, EE, nullptr, f3, EE, EE, 0);
        fmha16_k<<<gmha, 256, 0, stream>>>(f1, f2, f3, nullptr, f4, NN, NN);
        gemm_mfma_k<<<g4, 256, 0, stream>>>(f4, EE, wc, EE, Wcb + i * EE, f1, EE, EE, 0);
        inorm_k<<<BB * EE, 64, 0, stream>>>(f0, f1, n1g + i * EE, n1b + i * EE, f5);
        gemm_mfma_k<<<g16, 256, 0, stream>>>(f5, EE, fW1 + (size_t)i * FFH_ * EE, EE, fb1 + i * FFH_, big, FFH_, EE, 1);
        gemm_mfma_k<<<g4, 256, 0, stream>>>(big, FFH_, fW2 + (size_t)i * EE * FFH_, FFH_, fb2 + i * EE, f1, EE, FFH_, 0);
        inorm_k<<<BB * EE, 64, 0, stream>>>(f5, f1, n2g + i * EE, n2b + i * EE, f0);
    }

    // ---- decoder ----
    gemm_mfma_k<<<g4, 256, 0, stream>>>(f0, EE, dWk, EE, nullptr, f1, EE, EE, 0);
    gemm_mfma_k<<<g4, 256, 0, stream>>>(f0, EE, dWv, EE, nullptr, f2, EE, EE, 0);

    zero_k<<<(BB * EE + 255) / 256, 256, 0, stream>>>(f3, BB * EE);
    encsum_k<<<dim3(BB, 8), 128, 0, stream>>>(f0, f3);
    meanterm_k<<<BB, 128, 0, stream>>>(f3, Wqr, f3 + BB * EE);

    subtour_k<<<BB * MM, 128, 0, stream>>>(f0, subn, subl, f4);
    decq_k<<<BB * MM, 128, 0, stream>>>(f0, f4, f3 + BB * EE, cur, loadv, sel, Wql, Wqr, f5);

    fmha16_k<<<gmha, 256, 0, stream>>>(f5, f1, f2, mask, f4, MM, NN);
    // dec score -> big (keeps f1..f5 free for the logits matrix)
    gemm_mfma_k<<<g4, 256, 0, stream>>>(f4, EE, dWc, EE, dWcb, big, EE, EE, 0);

    // logits (B x 520 x 520) at f1 (spans f1..f5; all dead now)
    sgemm_k<<<gsc, 256, 0, stream>>>(big, f0, f1);
    smax_k<<<BB * MM, 64, 0, stream>>>(f1, mask, (float*)d_out);
}

// Round 2
// 2034.167 us; speedup vs baseline: 1.3261x; 1.0305x over previous
//
#include <hip/hip_runtime.h>
#include <hip/hip_bf16.h>

#define BB 32
#define NN 520
#define MM 520
#define EE 128
#define HH 8
#define DKK 16
#define FFH_ 512
#define NL_ 6
#define DEPOT_ 20
#define LL 40

typedef short short8 __attribute__((ext_vector_type(8)));
typedef short bshort4 __attribute__((ext_vector_type(4)));
typedef float floatx4 __attribute__((ext_vector_type(4)));

__device__ __forceinline__ unsigned short f2b(float x) {
    unsigned int u = __float_as_uint(x);
    return (unsigned short)((u + 0x7fffu + ((u >> 16) & 1u)) >> 16);
}
__device__ __forceinline__ float b2f_(unsigned short h) {
    return __uint_as_float(((unsigned int)h) << 16);
}

// ---------------- embedding: depot/customer linear ----------------
__global__ __launch_bounds__(256) void embed_k(
    const float* __restrict__ dep, const float* __restrict__ cus,
    const float* __restrict__ Wd, const float* __restrict__ bd,
    const float* __restrict__ Wc3, const float* __restrict__ bc,
    float* __restrict__ x)
{
    int idx = blockIdx.x * 256 + threadIdx.x;   // < B*N*E = 2129920
    int e = idx & 127;
    int bn = idx >> 7;
    int n = bn % NN;
    int b = bn / NN;
    float a;
    if (n < DEPOT_) {
        a = bd[e];
        const float* f = dep + ((size_t)(b * DEPOT_ + n)) * 4;
        #pragma unroll
        for (int j = 0; j < 4; j++) a += f[j] * Wd[e * 4 + j];
    } else {
        a = bc[e];
        const float* f = cus + ((size_t)(b * 500 + (n - DEPOT_))) * 3;
        #pragma unroll
        for (int j = 0; j < 3; j++) a += f[j] * Wc3[e * 3 + j];
    }
    x[idx] = a;
}

// ---------------- bf16x3 MFMA GEMM: C[m,n] = sum_k A[m,k]*W[n,k] + bias[n] ----------------
// Block tile 128(m) x 64(n), BK=32, 4 waves. Each value split a = hi(bf16) + lo(bf16);
// A*B ~= AhBh + AhBl + AlBh (error ~2^-17 relative, fp32-equivalent here).
// Frag layouts (verified m89/m120): A/B idx=lane&15, k=(lane>>4)*8+j; C col=lane&15,
// row=(lane>>4)*4+reg. Rows padded to 40 shorts (80B) -> 16B-aligned, 2-way banks (free).
#define AP 40
__global__ __launch_bounds__(256) void gemm_mfma_k(
    const float* __restrict__ A, int lda,
    const float* __restrict__ W, int ldw,
    const float* __restrict__ bias,
    float* __restrict__ C, int ldc,
    int K, int relu)
{
    __shared__ __align__(16) unsigned short Ah[128][AP];
    __shared__ __align__(16) unsigned short Al[128][AP];
    __shared__ __align__(16) unsigned short Bh[64][AP];
    __shared__ __align__(16) unsigned short Bl[64][AP];

    int t = threadIdx.x;
    int w = t >> 6, lane = t & 63;
    int frow = lane & 15, fq = lane >> 4;
    int n0 = blockIdx.x * 64, m0 = blockIdx.y * 128;

    int arow = t & 127, ahalf = (t >> 7) * 16;   // A: 128 rows x 32 cols, 16 floats/thread
    int brow = t & 63,  bq    = (t >> 6) * 8;    // B: 64 rows x 32 cols, 8 floats/thread

    floatx4 acc[2][4];
    #pragma unroll
    for (int i = 0; i < 2; i++)
        #pragma unroll
        for (int j = 0; j < 4; j++)
            acc[i][j] = (floatx4){0.0f, 0.0f, 0.0f, 0.0f};

    for (int k0 = 0; k0 < K; k0 += 32) {
        // ---- stage A (hi/lo bf16) ----
        {
            const float* Ap = A + (size_t)(m0 + arow) * lda + k0 + ahalf;
            float vr[16];
            #pragma unroll
            for (int j = 0; j < 4; j++) {
                float4 v = ((const float4*)Ap)[j];
                vr[j * 4 + 0] = v.x; vr[j * 4 + 1] = v.y;
                vr[j * 4 + 2] = v.z; vr[j * 4 + 3] = v.w;
            }
            short8 hv0, hv1, lv0, lv1;
            #pragma unroll
            for (int j = 0; j < 8; j++) {
                unsigned short h = f2b(vr[j]);
                hv0[j] = (short)h;
                lv0[j] = (short)f2b(vr[j] - b2f_(h));
            }
            #pragma unroll
            for (int j = 0; j < 8; j++) {
                unsigned short h = f2b(vr[8 + j]);
                hv1[j] = (short)h;
                lv1[j] = (short)f2b(vr[8 + j] - b2f_(h));
            }
            *((short8*)&Ah[arow][ahalf])     = hv0;
            *((short8*)&Ah[arow][ahalf + 8]) = hv1;
            *((short8*)&Al[arow][ahalf])     = lv0;
            *((short8*)&Al[arow][ahalf + 8]) = lv1;
        }
        // ---- stage B (hi/lo bf16) ----
        {
            const float* Wp = W + (size_t)(n0 + brow) * ldw + k0 + bq;
            float4 v0 = ((const float4*)Wp)[0];
            float4 v1 = ((const float4*)Wp)[1];
            float wr[8] = {v0.x, v0.y, v0.z, v0.w, v1.x, v1.y, v1.z, v1.w};
            short8 hv, lv;
            #pragma unroll
            for (int j = 0; j < 8; j++) {
                unsigned short h = f2b(wr[j]);
                hv[j] = (short)h;
                lv[j] = (short)f2b(wr[j] - b2f_(h));
            }
            *((short8*)&Bh[brow][bq]) = hv;
            *((short8*)&Bl[brow][bq]) = lv;
        }
        __syncthreads();

        // ---- MFMA: 2 m-tiles x 4 n-tiles x 3 passes ----
        short8 ah0 = *((const short8*)&Ah[w * 32 + frow][fq * 8]);
        short8 ah1 = *((const short8*)&Ah[w * 32 + 16 + frow][fq * 8]);
        short8 al0 = *((const short8*)&Al[w * 32 + frow][fq * 8]);
        short8 al1 = *((const short8*)&Al[w * 32 + 16 + frow][fq * 8]);
        #pragma unroll
        for (int nt = 0; nt < 4; nt++) {
            short8 bh = *((const short8*)&Bh[nt * 16 + frow][fq * 8]);
            short8 bl = *((const short8*)&Bl[nt * 16 + frow][fq * 8]);
            acc[0][nt] = __builtin_amdgcn_mfma_f32_16x16x32_bf16(ah0, bh, acc[0][nt], 0, 0, 0);
            acc[1][nt] = __builtin_amdgcn_mfma_f32_16x16x32_bf16(ah1, bh, acc[1][nt], 0, 0, 0);
            acc[0][nt] = __builtin_amdgcn_mfma_f32_16x16x32_bf16(ah0, bl, acc[0][nt], 0, 0, 0);
            acc[1][nt] = __builtin_amdgcn_mfma_f32_16x16x32_bf16(ah1, bl, acc[1][nt], 0, 0, 0);
            acc[0][nt] = __builtin_amdgcn_mfma_f32_16x16x32_bf16(al0, bh, acc[0][nt], 0, 0, 0);
            acc[1][nt] = __builtin_amdgcn_mfma_f32_16x16x32_bf16(al1, bh, acc[1][nt], 0, 0, 0);
        }
        __syncthreads();
    }

    // ---- epilogue ----
    #pragma unroll
    for (int nt = 0; nt < 4; nt++) {
        int col = n0 + nt * 16 + frow;
        float bv = bias ? bias[col] : 0.0f;
        #pragma unroll
        for (int mt = 0; mt < 2; mt++) {
            int rbase = m0 + w * 32 + mt * 16 + fq * 4;
            #pragma unroll
            for (int r = 0; r < 4; r++) {
                float v = acc[mt][nt][r] + bv;
                if (relu) v = fmaxf(v, 0.0f);
                C[(size_t)(rbase + r) * ldc + col] = v;
            }
        }
    }
}

// ---------------- score GEMM (NT) with tanh epilogue (fp32) ----------------
#define GT 64
#define GK 32
#define GP 36
__global__ __launch_bounds__(256) void sgemm_k(
    const float* __restrict__ A,    // score [B*520][128]
    const float* __restrict__ Enc,  // [B*520][128]
    float* __restrict__ C)          // [B][520][520]
{
    __shared__ float As[GT][GP];
    __shared__ float Ws[GT][GP];
    int t = threadIdx.x;
    int tx = t & 15, ty = t >> 4;
    int b = blockIdx.z;
    int m0 = blockIdx.y * GT, n0 = blockIdx.x * GT;
    int lr = t >> 2, lc = (t & 3) * 8;
    int mr = m0 + lr; if (mr >= NN) mr = NN - 1;
    int nr = n0 + lr; if (nr >= NN) nr = NN - 1;
    float acc[4][4];
    #pragma unroll
    for (int i = 0; i < 4; i++)
        #pragma unroll
        for (int j = 0; j < 4; j++) acc[i][j] = 0.0f;

    for (int k0 = 0; k0 < EE; k0 += GK) {
        const float* Ap = A + ((size_t)(b * NN + mr)) * EE + k0 + lc;
        const float* Wp = Enc + ((size_t)(b * NN + nr)) * EE + k0 + lc;
        float4 av0 = *((const float4*)Ap), av1 = *((const float4*)(Ap + 4));
        float4 wv0 = *((const float4*)Wp), wv1 = *((const float4*)(Wp + 4));
        *((float4*)&As[lr][lc]) = av0; *((float4*)&As[lr][lc + 4]) = av1;
        *((float4*)&Ws[lr][lc]) = wv0; *((float4*)&Ws[lr][lc + 4]) = wv1;
        __syncthreads();
        #pragma unroll
        for (int kk = 0; kk < GK; kk += 2) {
            float2 a0 = *((const float2*)&As[ty][kk]);
            float2 a1 = *((const float2*)&As[ty + 16][kk]);
            float2 a2 = *((const float2*)&As[ty + 32][kk]);
            float2 a3 = *((const float2*)&As[ty + 48][kk]);
            float2 w0 = *((const float2*)&Ws[tx][kk]);
            float2 w1 = *((const float2*)&Ws[tx + 16][kk]);
            float2 w2 = *((const float2*)&Ws[tx + 32][kk]);
            float2 w3 = *((const float2*)&Ws[tx + 48][kk]);
            acc[0][0] += a0.x * w0.x + a0.y * w0.y;
            acc[0][1] += a0.x * w1.x + a0.y * w1.y;
            acc[0][2] += a0.x * w2.x + a0.y * w2.y;
            acc[0][3] += a0.x * w3.x + a0.y * w3.y;
            acc[1][0] += a1.x * w0.x + a1.y * w0.y;
            acc[1][1] += a1.x * w1.x + a1.y * w1.y;
            acc[1][2] += a1.x * w2.x + a1.y * w2.y;
            acc[1][3] += a1.x * w3.x + a1.y * w3.y;
            acc[2][0] += a2.x * w0.x + a2.y * w0.y;
            acc[2][1] += a2.x * w1.x + a2.y * w1.y;
            acc[2][2] += a2.x * w2.x + a2.y * w2.y;
            acc[2][3] += a2.x * w3.x + a2.y * w3.y;
            acc[3][0] += a3.x * w0.x + a3.y * w0.y;
            acc[3][1] += a3.x * w1.x + a3.y * w1.y;
            acc[3][2] += a3.x * w2.x + a3.y * w2.y;
            acc[3][3] += a3.x * w3.x + a3.y * w3.y;
        }
        __syncthreads();
    }
    #pragma unroll
    for (int i = 0; i < 4; i++) {
        int m = m0 + ty + 16 * i;
        if (m >= NN) continue;
        #pragma unroll
        for (int j = 0; j < 4; j++) {
            int n = n0 + tx + 16 * j;
            if (n >= NN) continue;
            float v = 10.0f * tanhf(acc[i][j] * 0.088388347648318447f);
            C[((size_t)(b * NN + m)) * NN + n] = v;
        }
    }
}

// ---------------- row softmax: out = softmax(logits + mask) ----------------
__global__ __launch_bounds__(64) void smax_k(
    const float* __restrict__ L, const float* __restrict__ mask,
    float* __restrict__ out)
{
    int bm = blockIdx.x;
    int t = threadIdx.x;
    const float* Lr = L + (size_t)bm * NN;
    const float* Mr = mask + (size_t)bm * NN;
    float v[9];
    float mx = -1e30f;
    #pragma unroll
    for (int i = 0; i < 9; i++) {
        int idx = t + i * 64;
        if (idx < NN) { v[i] = Lr[idx] + Mr[idx]; mx = fmaxf(mx, v[i]); }
        else v[i] = -1e30f;
    }
    #pragma unroll
    for (int o = 32; o > 0; o >>= 1) mx = fmaxf(mx, __shfl_xor(mx, o));
    float s = 0.0f;
    #pragma unroll
    for (int i = 0; i < 9; i++) {
        int idx = t + i * 64;
        float e = (idx < NN) ? expf(v[i] - mx) : 0.0f;
        v[i] = e; s += e;
    }
    #pragma unroll
    for (int o = 32; o > 0; o >>= 1) s += __shfl_xor(s, o);
    float inv = 1.0f / s;
    #pragma unroll
    for (int i = 0; i < 9; i++) {
        int idx = t + i * 64;
        if (idx < NN) out[(size_t)bm * NN + idx] = v[i] * inv;
    }
}

// ---------------- MFMA flash attention v2 (bf16x3, fp32-equivalent) ----------------
// 4 waves, 128 q-rows/block (2 q-frags per wave), one (head, batch) slice.
// Swapped QK^T: S^T = mfma(A=K, B=Q): per lane q = lane&15, kc = 16s+4g+r.
// K/V LDS frags are loaded once per s and shared by both q-frags.
// Double-buffered LDS + async-stage split: next tile's global loads issue
// before this tile's compute; LDS write after; ONE barrier per iteration.
// Grid is (h, b, qt): gridDim.x=8 so flattened block id === h (mod 8) -> the
// round-robin XCD assignment pins each head's K/V slice (2.1 MB/XCD) into L2.
#define ATQ 128
#define ATK 64
__global__ __launch_bounds__(256) void fmha16_k(
    const float* __restrict__ Q, const float* __restrict__ K,
    const float* __restrict__ V, const float* __restrict__ mask,
    float* __restrict__ O, int Nq, int Nk)
{
    __shared__ __align__(16) unsigned short Khi[2][ATK][20];
    __shared__ __align__(16) unsigned short Klo[2][ATK][20];
    __shared__ __align__(16) unsigned short Vhi[2][16][72];
    __shared__ __align__(16) unsigned short Vlo[2][16][72];

    int h = blockIdx.x, b = blockIdx.y, qt = blockIdx.z;
    int t = threadIdx.x;
    int w = t >> 6, lane = t & 63;
    int r16 = lane & 15, g = lane >> 4;

    // ---- Q fragments (hi/lo bf16): frag i covers rows qt*128 + 64*i + w*16 + r16 ----
    int qbase[2];
    qbase[0] = qt * ATQ + w * 16;
    qbase[1] = qt * ATQ + 64 + w * 16;
    bshort4 qh[2], ql[2];
    const float* mrow[2] = {nullptr, nullptr};
    #pragma unroll
    for (int i = 0; i < 2; i++) {
        int qg = qbase[i] + r16;
        int qc = qg < Nq ? qg : Nq - 1;
        float4 qv = *((const float4*)(Q + ((size_t)(b * Nq + qc)) * EE + h * 16 + 4 * g));
        float qa[4] = {qv.x, qv.y, qv.z, qv.w};
        #pragma unroll
        for (int j = 0; j < 4; j++) {
            unsigned short hh = f2b(qa[j]);
            qh[i][j] = (short)hh;
            ql[i][j] = (short)f2b(qa[j] - b2f_(hh));
        }
        if (mask) mrow[i] = mask + ((size_t)(b * Nq + qc)) * Nk;
    }

    floatx4 o_acc[2];
    o_acc[0] = (floatx4){0.0f, 0.0f, 0.0f, 0.0f};
    o_acc[1] = (floatx4){0.0f, 0.0f, 0.0f, 0.0f};
    float m_i[2] = {-1e30f, -1e30f};
    float l_i[2] = {0.0f, 0.0f};

    int skr = t >> 2;          // staging k-row 0..63
    int sc  = (t & 3) * 4;     // staging col 0/4/8/12
    const float* Kbase = K + ((size_t)b * Nk) * EE + h * 16 + sc;
    const float* Vbase = V + ((size_t)b * Nk) * EE + h * 16 + sc;

    // ---- prologue: stage tile 0 into buffer 0 ----
    {
        int krc = skr < Nk ? skr : Nk - 1;
        float4 kv = *((const float4*)(Kbase + (size_t)krc * EE));
        float4 vv = *((const float4*)(Vbase + (size_t)krc * EE));
        float ka[4] = {kv.x, kv.y, kv.z, kv.w};
        float va[4] = {vv.x, vv.y, vv.z, vv.w};
        bshort4 khv, klv;
        #pragma unroll
        for (int j = 0; j < 4; j++) {
            unsigned short hh = f2b(ka[j]);
            khv[j] = (short)hh;
            klv[j] = (short)f2b(ka[j] - b2f_(hh));
        }
        *((bshort4*)&Khi[0][skr][sc]) = khv;
        *((bshort4*)&Klo[0][skr][sc]) = klv;
        #pragma unroll
        for (int j = 0; j < 4; j++) {
            unsigned short hh = f2b(va[j]);
            Vhi[0][sc + j][skr] = hh;
            Vlo[0][sc + j][skr] = (unsigned short)f2b(va[j] - b2f_(hh));
        }
    }
    __syncthreads();

    int nkt = (Nk + ATK - 1) / ATK;
    for (int kt = 0; kt < nkt; kt++) {
        int cur = kt & 1;
        int k0 = kt * ATK;

        // ---- issue next tile's global loads (latency hides under compute) ----
        float4 nkv, nvv;
        bool pf = (kt + 1 < nkt);
        if (pf) {
            int kr = k0 + ATK + skr;
            int krc = kr < Nk ? kr : Nk - 1;
            nkv = *((const float4*)(Kbase + (size_t)krc * EE));
            nvv = *((const float4*)(Vbase + (size_t)krc * EE));
        }

        // ---- S^T: 4 sub-tiles x 3 passes; K frag shared by both q-frags ----
        float p[2][4][4];
        #pragma unroll
        for (int s = 0; s < 4; s++) {
            bshort4 kh = *((const bshort4*)&Khi[cur][s * 16 + r16][4 * g]);
            bshort4 kl = *((const bshort4*)&Klo[cur][s * 16 + r16][4 * g]);
            #pragma unroll
            for (int i = 0; i < 2; i++) {
                floatx4 acc = (floatx4){0.0f, 0.0f, 0.0f, 0.0f};
                acc = __builtin_amdgcn_mfma_f32_16x16x16bf16_1k(kh, qh[i], acc, 0, 0, 0);
                acc = __builtin_amdgcn_mfma_f32_16x16x16bf16_1k(kh, ql[i], acc, 0, 0, 0);
                acc = __builtin_amdgcn_mfma_f32_16x16x16bf16_1k(kl, qh[i], acc, 0, 0, 0);
                #pragma unroll
                for (int r = 0; r < 4; r++) p[i][s][r] = acc[r];
            }
        }

        // ---- scale + bounds ----
        #pragma unroll
        for (int i = 0; i < 2; i++)
            #pragma unroll
            for (int s = 0; s < 4; s++)
                #pragma unroll
                for (int r = 0; r < 4; r++) {
                    int kc = k0 + s * 16 + 4 * g + r;
                    p[i][s][r] = (kc < Nk) ? p[i][s][r] * 0.25f : -1e30f;
                }
        // ---- mask add (decoder only), float4 fast path ----
        if (mask) {
            #pragma unroll
            for (int i = 0; i < 2; i++) {
                #pragma unroll
                for (int s = 0; s < 4; s++) {
                    int c0 = k0 + s * 16 + 4 * g;
                    float mv[4];
                    if (c0 + 3 < Nk) {
                        float4 m4 = *((const float4*)(mrow[i] + c0));
                        mv[0] = m4.x; mv[1] = m4.y; mv[2] = m4.z; mv[3] = m4.w;
                    } else {
                        #pragma unroll
                        for (int r = 0; r < 4; r++)
                            mv[r] = (c0 + r < Nk) ? mrow[i][c0 + r] : 0.0f;
                    }
                    #pragma unroll
                    for (int r = 0; r < 4; r++) p[i][s][r] += mv[r];
                }
            }
        }

        // ---- online softmax (per q = lane&15, per frag) ----
        #pragma unroll
        for (int i = 0; i < 2; i++) {
            float tmax = -1e30f;
            #pragma unroll
            for (int s = 0; s < 4; s++)
                #pragma unroll
                for (int r = 0; r < 4; r++) tmax = fmaxf(tmax, p[i][s][r]);
            tmax = fmaxf(tmax, __shfl_xor(tmax, 16));
            tmax = fmaxf(tmax, __shfl_xor(tmax, 32));
            float m_new = fmaxf(m_i[i], tmax);
            float alpha = __expf(m_i[i] - m_new);
            float lloc = 0.0f;
            #pragma unroll
            for (int s = 0; s < 4; s++) {
                #pragma unroll
                for (int r = 0; r < 4; r++) {
                    float e = __expf(p[i][s][r] - m_new);
                    p[i][s][r] = e; lloc += e;
                }
            }
            lloc += __shfl_xor(lloc, 16);
            lloc += __shfl_xor(lloc, 32);
            l_i[i] = l_i[i] * alpha + lloc;
            m_i[i] = m_new;
            #pragma unroll
            for (int r = 0; r < 4; r++) {
                float ar = __shfl(alpha, 4 * g + r);
                o_acc[i][r] *= ar;
            }
        }

        // ---- PV: p is the A-frag already; V frag shared by both q-frags ----
        #pragma unroll
        for (int s = 0; s < 4; s++) {
            bshort4 vh = *((const bshort4*)&Vhi[cur][r16][s * 16 + 4 * g]);
            bshort4 vl = *((const bshort4*)&Vlo[cur][r16][s * 16 + 4 * g]);
            #pragma unroll
            for (int i = 0; i < 2; i++) {
                bshort4 ph, pl;
                #pragma unroll
                for (int r = 0; r < 4; r++) {
                    unsigned short hh = f2b(p[i][s][r]);
                    ph[r] = (short)hh;
                    pl[r] = (short)f2b(p[i][s][r] - b2f_(hh));
                }
                o_acc[i] = __builtin_amdgcn_mfma_f32_16x16x16bf16_1k(ph, vh, o_acc[i], 0, 0, 0);
                o_acc[i] = __builtin_amdgcn_mfma_f32_16x16x16bf16_1k(ph, vl, o_acc[i], 0, 0, 0);
                o_acc[i] = __builtin_amdgcn_mfma_f32_16x16x16bf16_1k(pl, vh, o_acc[i], 0, 0, 0);
            }
        }

        // ---- write next tile into the other buffer (vmcnt wait lands here) ----
        if (pf) {
            int nb = cur ^ 1;
            float ka[4] = {nkv.x, nkv.y, nkv.z, nkv.w};
            float va[4] = {nvv.x, nvv.y, nvv.z, nvv.w};
            bshort4 khv, klv;
            #pragma unroll
            for (int j = 0; j < 4; j++) {
                unsigned short hh = f2b(ka[j]);
                khv[j] = (short)hh;
                klv[j] = (short)f2b(ka[j] - b2f_(hh));
            }
            *((bshort4*)&Khi[nb][skr][sc]) = khv;
            *((bshort4*)&Klo[nb][skr][sc]) = klv;
            #pragma unroll
            for (int j = 0; j < 4; j++) {
                unsigned short hh = f2b(va[j]);
                Vhi[nb][sc + j][skr] = hh;
                Vlo[nb][sc + j][skr] = (unsigned short)f2b(va[j] - b2f_(hh));
            }
        }
        __syncthreads();
    }

    // ---- epilogue: O reg r is (q-row 4g+r, d = r16); l lives at lane q ----
    #pragma unroll
    for (int i = 0; i < 2; i++) {
        #pragma unroll
        for (int r = 0; r < 4; r++) {
            float lr = __shfl(l_i[i], 4 * g + r);
            int qrow = qbase[i] + 4 * g + r;
            if (qrow < Nq)
                O[((size_t)(b * Nq + qrow)) * EE + h * 16 + r16] = o_acc[i][r] / lr;
        }
    }
}

// ---------------- InstanceNorm over node axis ----------------
__global__ __launch_bounds__(64) void inorm_k(
    const float* __restrict__ X, const float* __restrict__ Y,
    const float* __restrict__ g, const float* __restrict__ bb,
    float* __restrict__ Out)
{
    int be = blockIdx.x;
    int b = be >> 7, e = be & 127;
    int t = threadIdx.x;
    float vals[9];
    float s = 0.0f, s2 = 0.0f;
    int c = 0;
    for (int n = t; n < NN; n += 64) {
        size_t off = ((size_t)(b * NN + n)) * EE + e;
        float v = X[off] + Y[off];
        vals[c++] = v; s += v; s2 += v * v;
    }
    #pragma unroll
    for (int o = 32; o > 0; o >>= 1) { s += __shfl_down(s, o); s2 += __shfl_down(s2, o); }
    s = __shfl(s, 0); s2 = __shfl(s2, 0);
    float mu = s * (1.0f / NN);
    float var = s2 * (1.0f / NN) - mu * mu;
    float inv = rsqrtf(var + 1e-5f);
    float gg = g[e], bv = bb[e];
    c = 0;
    for (int n = t; n < NN; n += 64) {
        size_t off = ((size_t)(b * NN + n)) * EE + e;
        Out[off] = (vals[c++] - mu) * inv * gg + bv;
    }
}

__global__ void zero_k(float* p, int n) {
    int i = blockIdx.x * 256 + threadIdx.x;
    if (i < n) p[i] = 0.0f;
}

__global__ __launch_bounds__(128) void encsum_k(const float* __restrict__ enc, float* __restrict__ esum) {
    int b = blockIdx.x, ch = blockIdx.y, t = threadIdx.x;
    float a = 0.0f;
    for (int i = 0; i < 65; i++) {
        int n = ch * 65 + i;
        a += enc[((size_t)(b * NN + n)) * EE + t];
    }
    atomicAdd(&esum[b * EE + t], a);
}

// mt[b,e] = sum_f (esum[b,f]/N) * Wr[e, 128+f]
__global__ __launch_bounds__(128) void meanterm_k(
    const float* __restrict__ esum, const float* __restrict__ Wr, float* __restrict__ mt)
{
    int b = blockIdx.x, t = threadIdx.x;
    __shared__ float em[128];
    em[t] = esum[b * EE + t] * (1.0f / NN);
    __syncthreads();
    const float* w = Wr + (size_t)t * 257 + 128;
    float a = 0.0f;
    for (int f = 0; f < 128; f++) a += em[f] * w[f];
    mt[b * EE + t] = a;
}

__global__ __launch_bounds__(128) void subtour_k(
    const float* __restrict__ enc, const int* __restrict__ subn,
    const int* __restrict__ subl, float* __restrict__ subm)
{
    int bm = blockIdx.x;
    int b = bm / MM;
    int t = threadIdx.x;
    int len = subl[bm];
    float acc = 0.0f; int cnt = 0;
    for (int l = 0; l < LL; l++) {
        int node = subn[(size_t)bm * LL + l];
        if (l < len && node >= DEPOT_) {
            acc += enc[((size_t)(b * NN + node)) * EE + t];
            cnt++;
        }
    }
    float cf = (float)(cnt < 1 ? 1 : cnt);
    subm[(size_t)bm * EE + t] = acc / cf;
}

__global__ __launch_bounds__(128) void decq_k(
    const float* __restrict__ enc, const float* __restrict__ subm,
    const float* __restrict__ mterm, const int* __restrict__ cur,
    const float* __restrict__ loadv, const int* __restrict__ sel,
    const float* __restrict__ Wl, const float* __restrict__ Wr,
    float* __restrict__ out)
{
    int bm = blockIdx.x;
    int b = bm / MM;
    int t = threadIdx.x;
    __shared__ float le[128], sm[128];
    int cn = cur[bm];
    le[t] = enc[((size_t)(b * NN + cn)) * EE + t];
    sm[t] = subm[(size_t)bm * EE + t];
    __syncthreads();
    int s2v = sel[(size_t)bm * 4 + 2];   // selected[:,:,-2]
    bool flag = (s2v >= DEPOT_) && (cn < DEPOT_);
    float q;
    if (flag) {
        const float* w = Wl + (size_t)t * 256;
        float a = 0.0f;
        for (int f = 0; f < 128; f++) a += le[f] * w[f];
        for (int f = 0; f < 128; f++) a += sm[f] * w[128 + f];
        q = a;
    } else {
        const float* w = Wr + (size_t)t * 257;
        float a = mterm[b * EE + t] + loadv[bm] * w[256];
        for (int f = 0; f < 128; f++) a += le[f] * w[f];
        q = a;
    }
    out[(size_t)bm * EE + t] = q;
}

extern "C" void kernel_launch(void* const* d_in, const int* in_sizes, int n_in,
                              void* d_out, int out_size, void* d_ws, size_t ws_size,
                              hipStream_t stream)
{
    const float* depot = (const float*)d_in[0];
    const float* cust  = (const float*)d_in[1];
    const float* mask  = (const float*)d_in[2];
    const float* loadv = (const float*)d_in[3];
    const int*  cur   = (const int*)d_in[4];
    const int*  subn  = (const int*)d_in[5];
    const int*  subl  = (const int*)d_in[6];
    const int*  sel   = (const int*)d_in[7];
    const float* Wdep  = (const float*)d_in[8];
    const float* bdep  = (const float*)d_in[9];
    const float* Wcus  = (const float*)d_in[10];
    const float* bcus  = (const float*)d_in[11];
    const float* Wq    = (const float*)d_in[12];
    const float* Wk    = (const float*)d_in[13];
    const float* Wv    = (const float*)d_in[14];
    const float* Wc    = (const float*)d_in[15];
    const float* Wcb   = (const float*)d_in[16];
    const float* n1g   = (const float*)d_in[17];
    const float* n1b   = (const float*)d_in[18];
    const float* fW1   = (const float*)d_in[19];
    const float* fb1   = (const float*)d_in[20];
    const float* fW2   = (const float*)d_in[21];
    const float* fb2   = (const float*)d_in[22];
    const float* n2g   = (const float*)d_in[23];
    const float* n2b   = (const float*)d_in[24];
    const float* Wql   = (const float*)d_in[25];
    const float* Wqr   = (const float*)d_in[26];
    const float* dWk   = (const float*)d_in[27];
    const float* dWv   = (const float*)d_in[28];
    const float* dWc   = (const float*)d_in[29];
    const float* dWcb  = (const float*)d_in[30];

    const size_t SZ = (size_t)BB * NN * EE;           // 2,129,920
    float* f0 = (float*)d_ws;       // x / encoded
    float* f1 = f0 + SZ;            // q / k_d / logits (spans f1..f5)
    float* f2 = f1 + SZ;            // k / v_d
    float* f3 = f2 + SZ;            // v / encsum + meanterm
    float* f4 = f3 + SZ;            // mh,ff2 out / sub_mean, dec attn
    float* f5 = f4 + SZ;            // x1 / final_q
    float* big = f5 + SZ;           // ffh (B*N*FFH) / dec score

    dim3 g4(EE / 64, (BB * NN) / 128);     // (2, 130)
    dim3 g16(FFH_ / 64, (BB * NN) / 128);  // (8, 130)
    dim3 gmha(HH, BB, (NN + ATQ - 1) / ATQ);  // (8, 32, 5): blockid%8==head -> XCD-pinned K/V
    dim3 gsc((NN + GT - 1) / GT, (NN + GT - 1) / GT, BB);  // (9, 9, 32)

    embed_k<<<(BB * NN * EE) / 256, 256, 0, stream>>>(depot, cust, Wdep, bdep, Wcus, bcus, f0);

    for (int i = 0; i < NL_; i++) {
        const float* wq = Wq + (size_t)i * EE * EE;
        const float* wk = Wk + (size_t)i * EE * EE;
        const float* wv = Wv + (size_t)i * EE * EE;
        const float* wc = Wc + (size_t)i * EE * EE;
        gemm_mfma_k<<<g4, 256, 0, stream>>>(f0, EE, wq, EE, nullptr, f1, EE, EE, 0);
        gemm_mfma_k<<<g4, 256, 0, stream>>>(f0, EE, wk, EE, nullptr, f2, EE, EE, 0);
        gemm_mfma_k<<<g4, 256, 0, stream>>>(f0, EE, wv, EE, nullptr, f3, EE, EE, 0);
        fmha16_k<<<gmha, 256, 0, stream>>>(f1, f2, f3, nullptr, f4, NN, NN);
        gemm_mfma_k<<<g4, 256, 0, stream>>>(f4, EE, wc, EE, Wcb + i * EE, f1, EE, EE, 0);
        inorm_k<<<BB * EE, 64, 0, stream>>>(f0, f1, n1g + i * EE, n1b + i * EE, f5);
        gemm_mfma_k<<<g16, 256, 0, stream>>>(f5, EE, fW1 + (size_t)i * FFH_ * EE, EE, fb1 + i * FFH_, big, FFH_, EE, 1);
        gemm_mfma_k<<<g4, 256, 0, stream>>>(big, FFH_, fW2 + (size_t)i * EE * FFH_, FFH_, fb2 + i * EE, f1, EE, FFH_, 0);
        inorm_k<<<BB * EE, 64, 0, stream>>>(f5, f1, n2g + i * EE, n2b + i * EE, f0);
    }

    // ---- decoder ----
    gemm_mfma_k<<<g4, 256, 0, stream>>>(f0, EE, dWk, EE, nullptr, f1, EE, EE, 0);
    gemm_mfma_k<<<g4, 256, 0, stream>>>(f0, EE, dWv, EE, nullptr, f2, EE, EE, 0);

    zero_k<<<(BB * EE + 255) / 256, 256, 0, stream>>>(f3, BB * EE);
    encsum_k<<<dim3(BB, 8), 128, 0, stream>>>(f0, f3);
    meanterm_k<<<BB, 128, 0, stream>>>(f3, Wqr, f3 + BB * EE);

    subtour_k<<<BB * MM, 128, 0, stream>>>(f0, subn, subl, f4);
    decq_k<<<BB * MM, 128, 0, stream>>>(f0, f4, f3 + BB * EE, cur, loadv, sel, Wql, Wqr, f5);

    fmha16_k<<<gmha, 256, 0, stream>>>(f5, f1, f2, mask, f4, MM, NN);
    // dec score -> big (keeps f1..f5 free for the logits matrix)
    gemm_mfma_k<<<g4, 256, 0, stream>>>(f4, EE, dWc, EE, dWcb, big, EE, EE, 0);

    // logits (B x 520 x 520) at f1 (spans f1..f5; all dead now)
    sgemm_k<<<gsc, 256, 0, stream>>>(big, f0, f1);
    smax_k<<<BB * MM, 64, 0, stream>>>(f1, mask, (float*)d_out);
}

// Round 3
// 1868.526 us; speedup vs baseline: 1.4437x; 1.0886x over previous
//
#include <hip/hip_runtime.h>
#include <hip/hip_bf16.h>

#define BB 32
#define NN 520
#define MM 520
#define EE 128
#define HH 8
#define DKK 16
#define FFH_ 512
#define NL_ 6
#define DEPOT_ 20
#define LL 40

typedef short short8 __attribute__((ext_vector_type(8)));
typedef short bshort4 __attribute__((ext_vector_type(4)));
typedef float floatx4 __attribute__((ext_vector_type(4)));

__device__ __forceinline__ unsigned short f2b(float x) {
    unsigned int u = __float_as_uint(x);
    return (unsigned short)((u + 0x7fffu + ((u >> 16) & 1u)) >> 16);
}
__device__ __forceinline__ float b2f_(unsigned short h) {
    return __uint_as_float(((unsigned int)h) << 16);
}

// ---------------- embedding: depot/customer linear ----------------
__global__ __launch_bounds__(256) void embed_k(
    const float* __restrict__ dep, const float* __restrict__ cus,
    const float* __restrict__ Wd, const float* __restrict__ bd,
    const float* __restrict__ Wc3, const float* __restrict__ bc,
    float* __restrict__ x)
{
    int idx = blockIdx.x * 256 + threadIdx.x;   // < B*N*E = 2129920
    int e = idx & 127;
    int bn = idx >> 7;
    int n = bn % NN;
    int b = bn / NN;
    float a;
    if (n < DEPOT_) {
        a = bd[e];
        const float* f = dep + ((size_t)(b * DEPOT_ + n)) * 4;
        #pragma unroll
        for (int j = 0; j < 4; j++) a += f[j] * Wd[e * 4 + j];
    } else {
        a = bc[e];
        const float* f = cus + ((size_t)(b * 500 + (n - DEPOT_))) * 3;
        #pragma unroll
        for (int j = 0; j < 3; j++) a += f[j] * Wc3[e * 3 + j];
    }
    x[idx] = a;
}

// ---------------- weight pre-conversion: fp32 -> hi/lo bf16 planes ----------------
// Arena layout (ushort offsets, per plane), one plane for hi one for lo:
//   per layer i (stride WLS):  [0)      qkv  [384][128]  (Wq;Wk;Wv rows)
//                              [49152)  wc   [128][128]
//                              [65536)  ffW1 [512][128]
//                              [131072) ffW2 [128][512]
//   dec (at WDEC):             [0)      dkv  [256][128]  (dWk;dWv)
//                              [32768)  dwc  [128][128]
//                              [49152)  rlq  [384][128]  (Wqr[:,:128]; Wql[:,:128]; Wql[:,128:256])
#define WLS 196608
#define WDEC 1179648
#define WTOT 1277952
__global__ __launch_bounds__(256) void wconv_k(
    const float* __restrict__ Wq, const float* __restrict__ Wk, const float* __restrict__ Wv,
    const float* __restrict__ Wc, const float* __restrict__ fW1, const float* __restrict__ fW2,
    const float* __restrict__ dWk, const float* __restrict__ dWv, const float* __restrict__ dWc,
    const float* __restrict__ Wql, const float* __restrict__ Wqr,
    unsigned short* __restrict__ WH, unsigned short* __restrict__ WL)
{
    int idx = blockIdx.x * 256 + threadIdx.x;
    if (idx >= WTOT) return;
    const float* src;
    if (idx < WDEC) {
        int i = idx / WLS, r = idx % WLS;
        if (r < 49152) {
            int row = r >> 7, col = r & 127;
            const float* w = row < 128 ? Wq : (row < 256 ? Wk : Wv);
            src = w + (size_t)i * 16384 + (size_t)(row & 127) * 128 + col;
        } else if (r < 65536) {
            src = Wc + (size_t)i * 16384 + (r - 49152);
        } else if (r < 131072) {
            src = fW1 + (size_t)i * 65536 + (r - 65536);
        } else {
            src = fW2 + (size_t)i * 65536 + (r - 131072);
        }
    } else {
        int r = idx - WDEC;
        if (r < 32768) {
            int row = r >> 7, col = r & 127;
            src = (row < 128 ? dWk : dWv) + (size_t)(row & 127) * 128 + col;
        } else if (r < 49152) {
            src = dWc + (r - 32768);
        } else {
            int rr = r - 49152;
            int row = rr >> 7, col = rr & 127;
            if (row < 128)      src = Wqr + (size_t)row * 257 + col;
            else if (row < 256) src = Wql + (size_t)(row - 128) * 256 + col;
            else                src = Wql + (size_t)(row - 256) * 256 + 128 + col;
        }
    }
    float v = *src;
    unsigned short h = f2b(v);
    WH[idx] = h;
    WL[idx] = f2b(v - b2f_(h));
}

// ---------------- bf16x3 MFMA GEMM with pre-converted weights ----------------
// C[m,n] = sum_k A[m,k]*W[n,k] + bias[n].  Block 128(m) x 64(n), BK=32, 4 waves.
// A staged fp32->hi/lo per k-iter; B copied straight from the pre-converted planes
// (two 16B vector loads/thread -- no conversion VALU in the loop).
#define AP 40
__global__ __launch_bounds__(256) void gemm_pc_k(
    const float* __restrict__ A, int lda,
    const unsigned short* __restrict__ WH, const unsigned short* __restrict__ WL, int ldw,
    const float* __restrict__ bias,
    float* __restrict__ C, int ldc,
    int K, int relu)
{
    __shared__ __align__(16) unsigned short Ah[128][AP];
    __shared__ __align__(16) unsigned short Al[128][AP];
    __shared__ __align__(16) unsigned short Bh[64][AP];
    __shared__ __align__(16) unsigned short Bl[64][AP];

    int t = threadIdx.x;
    int w = t >> 6, lane = t & 63;
    int frow = lane & 15, fq = lane >> 4;
    int n0 = blockIdx.x * 64, m0 = blockIdx.y * 128;

    int arow = t & 127, ahalf = (t >> 7) * 16;   // A: 128 rows x 32 cols
    int brow = t & 63,  bq    = (t >> 6) * 8;    // B: 64 rows x 32 cols

    floatx4 acc[2][4];
    #pragma unroll
    for (int i = 0; i < 2; i++)
        #pragma unroll
        for (int j = 0; j < 4; j++)
            acc[i][j] = (floatx4){0.0f, 0.0f, 0.0f, 0.0f};

    for (int k0 = 0; k0 < K; k0 += 32) {
        // ---- stage A (hi/lo bf16) ----
        {
            const float* Ap = A + (size_t)(m0 + arow) * lda + k0 + ahalf;
            float vr[16];
            #pragma unroll
            for (int j = 0; j < 4; j++) {
                float4 v = ((const float4*)Ap)[j];
                vr[j * 4 + 0] = v.x; vr[j * 4 + 1] = v.y;
                vr[j * 4 + 2] = v.z; vr[j * 4 + 3] = v.w;
            }
            short8 hv0, hv1, lv0, lv1;
            #pragma unroll
            for (int j = 0; j < 8; j++) {
                unsigned short h = f2b(vr[j]);
                hv0[j] = (short)h;
                lv0[j] = (short)f2b(vr[j] - b2f_(h));
            }
            #pragma unroll
            for (int j = 0; j < 8; j++) {
                unsigned short h = f2b(vr[8 + j]);
                hv1[j] = (short)h;
                lv1[j] = (short)f2b(vr[8 + j] - b2f_(h));
            }
            *((short8*)&Ah[arow][ahalf])     = hv0;
            *((short8*)&Ah[arow][ahalf + 8]) = hv1;
            *((short8*)&Al[arow][ahalf])     = lv0;
            *((short8*)&Al[arow][ahalf + 8]) = lv1;
        }
        // ---- stage B: straight copy of pre-converted planes ----
        {
            size_t wo = (size_t)(n0 + brow) * ldw + k0 + bq;
            *((short8*)&Bh[brow][bq]) = *((const short8*)(WH + wo));
            *((short8*)&Bl[brow][bq]) = *((const short8*)(WL + wo));
        }
        __syncthreads();

        short8 ah0 = *((const short8*)&Ah[w * 32 + frow][fq * 8]);
        short8 ah1 = *((const short8*)&Ah[w * 32 + 16 + frow][fq * 8]);
        short8 al0 = *((const short8*)&Al[w * 32 + frow][fq * 8]);
        short8 al1 = *((const short8*)&Al[w * 32 + 16 + frow][fq * 8]);
        #pragma unroll
        for (int nt = 0; nt < 4; nt++) {
            short8 bh = *((const short8*)&Bh[nt * 16 + frow][fq * 8]);
            short8 bl = *((const short8*)&Bl[nt * 16 + frow][fq * 8]);
            acc[0][nt] = __builtin_amdgcn_mfma_f32_16x16x32_bf16(ah0, bh, acc[0][nt], 0, 0, 0);
            acc[1][nt] = __builtin_amdgcn_mfma_f32_16x16x32_bf16(ah1, bh, acc[1][nt], 0, 0, 0);
            acc[0][nt] = __builtin_amdgcn_mfma_f32_16x16x32_bf16(ah0, bl, acc[0][nt], 0, 0, 0);
            acc[1][nt] = __builtin_amdgcn_mfma_f32_16x16x32_bf16(ah1, bl, acc[1][nt], 0, 0, 0);
            acc[0][nt] = __builtin_amdgcn_mfma_f32_16x16x32_bf16(al0, bh, acc[0][nt], 0, 0, 0);
            acc[1][nt] = __builtin_amdgcn_mfma_f32_16x16x32_bf16(al1, bh, acc[1][nt], 0, 0, 0);
        }
        __syncthreads();
    }

    #pragma unroll
    for (int nt = 0; nt < 4; nt++) {
        int col = n0 + nt * 16 + frow;
        float bv = bias ? bias[col] : 0.0f;
        #pragma unroll
        for (int mt = 0; mt < 2; mt++) {
            int rbase = m0 + w * 32 + mt * 16 + fq * 4;
            #pragma unroll
            for (int r = 0; r < 4; r++) {
                float v = acc[mt][nt][r] + bv;
                if (relu) v = fmaxf(v, 0.0f);
                C[(size_t)(rbase + r) * ldc + col] = v;
            }
        }
    }
}

// ---------------- fused 3-way GEMM (QKV / dec-KV / R+L1): one A pass, 3 outputs ----
// Weight plane holds the outputs stacked on the n axis ([384][128] or [256][128]).
// blockIdx.x selects the 64-wide n-slice; which = x>>1 picks the destination C.
__global__ __launch_bounds__(256) void gemm_qkv3_k(
    const float* __restrict__ A, int lda,
    const unsigned short* __restrict__ WH, const unsigned short* __restrict__ WL, int ldw,
    float* __restrict__ C0, float* __restrict__ C1, float* __restrict__ C2,
    int ldc, int K)
{
    __shared__ __align__(16) unsigned short Ah[128][AP];
    __shared__ __align__(16) unsigned short Al[128][AP];
    __shared__ __align__(16) unsigned short Bh[64][AP];
    __shared__ __align__(16) unsigned short Bl[64][AP];

    int t = threadIdx.x;
    int w = t >> 6, lane = t & 63;
    int frow = lane & 15, fq = lane >> 4;
    int nb = blockIdx.x;
    int which = nb >> 1;
    float* C = which == 0 ? C0 : (which == 1 ? C1 : C2);
    int n0w = nb * 64;            // row in stacked weight plane
    int n0c = (nb & 1) * 64;      // col in the selected C
    int m0 = blockIdx.y * 128;

    int arow = t & 127, ahalf = (t >> 7) * 16;
    int brow = t & 63,  bq    = (t >> 6) * 8;

    floatx4 acc[2][4];
    #pragma unroll
    for (int i = 0; i < 2; i++)
        #pragma unroll
        for (int j = 0; j < 4; j++)
            acc[i][j] = (floatx4){0.0f, 0.0f, 0.0f, 0.0f};

    for (int k0 = 0; k0 < K; k0 += 32) {
        {
            const float* Ap = A + (size_t)(m0 + arow) * lda + k0 + ahalf;
            float vr[16];
            #pragma unroll
            for (int j = 0; j < 4; j++) {
                float4 v = ((const float4*)Ap)[j];
                vr[j * 4 + 0] = v.x; vr[j * 4 + 1] = v.y;
                vr[j * 4 + 2] = v.z; vr[j * 4 + 3] = v.w;
            }
            short8 hv0, hv1, lv0, lv1;
            #pragma unroll
            for (int j = 0; j < 8; j++) {
                unsigned short h = f2b(vr[j]);
                hv0[j] = (short)h;
                lv0[j] = (short)f2b(vr[j] - b2f_(h));
            }
            #pragma unroll
            for (int j = 0; j < 8; j++) {
                unsigned short h = f2b(vr[8 + j]);
                hv1[j] = (short)h;
                lv1[j] = (short)f2b(vr[8 + j] - b2f_(h));
            }
            *((short8*)&Ah[arow][ahalf])     = hv0;
            *((short8*)&Ah[arow][ahalf + 8]) = hv1;
            *((short8*)&Al[arow][ahalf])     = lv0;
            *((short8*)&Al[arow][ahalf + 8]) = lv1;
        }
        {
            size_t wo = (size_t)(n0w + brow) * ldw + k0 + bq;
            *((short8*)&Bh[brow][bq]) = *((const short8*)(WH + wo));
            *((short8*)&Bl[brow][bq]) = *((const short8*)(WL + wo));
        }
        __syncthreads();

        short8 ah0 = *((const short8*)&Ah[w * 32 + frow][fq * 8]);
        short8 ah1 = *((const short8*)&Ah[w * 32 + 16 + frow][fq * 8]);
        short8 al0 = *((const short8*)&Al[w * 32 + frow][fq * 8]);
        short8 al1 = *((const short8*)&Al[w * 32 + 16 + frow][fq * 8]);
        #pragma unroll
        for (int nt = 0; nt < 4; nt++) {
            short8 bh = *((const short8*)&Bh[nt * 16 + frow][fq * 8]);
            short8 bl = *((const short8*)&Bl[nt * 16 + frow][fq * 8]);
            acc[0][nt] = __builtin_amdgcn_mfma_f32_16x16x32_bf16(ah0, bh, acc[0][nt], 0, 0, 0);
            acc[1][nt] = __builtin_amdgcn_mfma_f32_16x16x32_bf16(ah1, bh, acc[1][nt], 0, 0, 0);
            acc[0][nt] = __builtin_amdgcn_mfma_f32_16x16x32_bf16(ah0, bl, acc[0][nt], 0, 0, 0);
            acc[1][nt] = __builtin_amdgcn_mfma_f32_16x16x32_bf16(ah1, bl, acc[1][nt], 0, 0, 0);
            acc[0][nt] = __builtin_amdgcn_mfma_f32_16x16x32_bf16(al0, bh, acc[0][nt], 0, 0, 0);
            acc[1][nt] = __builtin_amdgcn_mfma_f32_16x16x32_bf16(al1, bh, acc[1][nt], 0, 0, 0);
        }
        __syncthreads();
    }

    #pragma unroll
    for (int nt = 0; nt < 4; nt++) {
        int col = n0c + nt * 16 + frow;
        #pragma unroll
        for (int mt = 0; mt < 2; mt++) {
            int rbase = m0 + w * 32 + mt * 16 + fq * 4;
            #pragma unroll
            for (int r = 0; r < 4; r++)
                C[(size_t)(rbase + r) * ldc + col] = acc[mt][nt][r];
        }
    }
}

// ---------------- score GEMM (NT) with tanh epilogue (fp32) ----------------
#define GT 64
#define GK 32
#define GP 36
__global__ __launch_bounds__(256) void sgemm_k(
    const float* __restrict__ A,    // score [B*520][128]
    const float* __restrict__ Enc,  // [B*520][128]
    float* __restrict__ C)          // [B][520][520]
{
    __shared__ float As[GT][GP];
    __shared__ float Ws[GT][GP];
    int t = threadIdx.x;
    int tx = t & 15, ty = t >> 4;
    int b = blockIdx.z;
    int m0 = blockIdx.y * GT, n0 = blockIdx.x * GT;
    int lr = t >> 2, lc = (t & 3) * 8;
    int mr = m0 + lr; if (mr >= NN) mr = NN - 1;
    int nr = n0 + lr; if (nr >= NN) nr = NN - 1;
    float acc[4][4];
    #pragma unroll
    for (int i = 0; i < 4; i++)
        #pragma unroll
        for (int j = 0; j < 4; j++) acc[i][j] = 0.0f;

    for (int k0 = 0; k0 < EE; k0 += GK) {
        const float* Ap = A + ((size_t)(b * NN + mr)) * EE + k0 + lc;
        const float* Wp = Enc + ((size_t)(b * NN + nr)) * EE + k0 + lc;
        float4 av0 = *((const float4*)Ap), av1 = *((const float4*)(Ap + 4));
        float4 wv0 = *((const float4*)Wp), wv1 = *((const float4*)(Wp + 4));
        *((float4*)&As[lr][lc]) = av0; *((float4*)&As[lr][lc + 4]) = av1;
        *((float4*)&Ws[lr][lc]) = wv0; *((float4*)&Ws[lr][lc + 4]) = wv1;
        __syncthreads();
        #pragma unroll
        for (int kk = 0; kk < GK; kk += 2) {
            float2 a0 = *((const float2*)&As[ty][kk]);
            float2 a1 = *((const float2*)&As[ty + 16][kk]);
            float2 a2 = *((const float2*)&As[ty + 32][kk]);
            float2 a3 = *((const float2*)&As[ty + 48][kk]);
            float2 w0 = *((const float2*)&Ws[tx][kk]);
            float2 w1 = *((const float2*)&Ws[tx + 16][kk]);
            float2 w2 = *((const float2*)&Ws[tx + 32][kk]);
            float2 w3 = *((const float2*)&Ws[tx + 48][kk]);
            acc[0][0] += a0.x * w0.x + a0.y * w0.y;
            acc[0][1] += a0.x * w1.x + a0.y * w1.y;
            acc[0][2] += a0.x * w2.x + a0.y * w2.y;
            acc[0][3] += a0.x * w3.x + a0.y * w3.y;
            acc[1][0] += a1.x * w0.x + a1.y * w0.y;
            acc[1][1] += a1.x * w1.x + a1.y * w1.y;
            acc[1][2] += a1.x * w2.x + a1.y * w2.y;
            acc[1][3] += a1.x * w3.x + a1.y * w3.y;
            acc[2][0] += a2.x * w0.x + a2.y * w0.y;
            acc[2][1] += a2.x * w1.x + a2.y * w1.y;
            acc[2][2] += a2.x * w2.x + a2.y * w2.y;
            acc[2][3] += a2.x * w3.x + a2.y * w3.y;
            acc[3][0] += a3.x * w0.x + a3.y * w0.y;
            acc[3][1] += a3.x * w1.x + a3.y * w1.y;
            acc[3][2] += a3.x * w2.x + a3.y * w2.y;
            acc[3][3] += a3.x * w3.x + a3.y * w3.y;
        }
        __syncthreads();
    }
    #pragma unroll
    for (int i = 0; i < 4; i++) {
        int m = m0 + ty + 16 * i;
        if (m >= NN) continue;
        #pragma unroll
        for (int j = 0; j < 4; j++) {
            int n = n0 + tx + 16 * j;
            if (n >= NN) continue;
            float v = 10.0f * tanhf(acc[i][j] * 0.088388347648318447f);
            C[((size_t)(b * NN + m)) * NN + n] = v;
        }
    }
}

// ---------------- row softmax: out = softmax(logits + mask) ----------------
__global__ __launch_bounds__(64) void smax_k(
    const float* __restrict__ L, const float* __restrict__ mask,
    float* __restrict__ out)
{
    int bm = blockIdx.x;
    int t = threadIdx.x;
    const float* Lr = L + (size_t)bm * NN;
    const float* Mr = mask + (size_t)bm * NN;
    float v[9];
    float mx = -1e30f;
    #pragma unroll
    for (int i = 0; i < 9; i++) {
        int idx = t + i * 64;
        if (idx < NN) { v[i] = Lr[idx] + Mr[idx]; mx = fmaxf(mx, v[i]); }
        else v[i] = -1e30f;
    }
    #pragma unroll
    for (int o = 32; o > 0; o >>= 1) mx = fmaxf(mx, __shfl_xor(mx, o));
    float s = 0.0f;
    #pragma unroll
    for (int i = 0; i < 9; i++) {
        int idx = t + i * 64;
        float e = (idx < NN) ? expf(v[i] - mx) : 0.0f;
        v[i] = e; s += e;
    }
    #pragma unroll
    for (int o = 32; o > 0; o >>= 1) s += __shfl_xor(s, o);
    float inv = 1.0f / s;
    #pragma unroll
    for (int i = 0; i < 9; i++) {
        int idx = t + i * 64;
        if (idx < NN) out[(size_t)bm * NN + idx] = v[i] * inv;
    }
}

// ---------------- MFMA flash attention v2 (bf16x3, fp32-equivalent) ----------------
// 4 waves, 128 q-rows/block (2 q-frags per wave), one (head, batch) slice.
// Swapped QK^T: S^T = mfma(A=K, B=Q): per lane q = lane&15, kc = 16s+4g+r.
// Double-buffered LDS + async-stage split; ONE barrier per iteration.
// Grid is (h, b, qt): gridDim.x=8 so flattened block id === h (mod 8) -> the
// round-robin XCD assignment pins each head's K/V slice into its L2.
#define ATQ 128
#define ATK 64
__global__ __launch_bounds__(256) void fmha16_k(
    const float* __restrict__ Q, const float* __restrict__ K,
    const float* __restrict__ V, const float* __restrict__ mask,
    float* __restrict__ O, int Nq, int Nk)
{
    __shared__ __align__(16) unsigned short Khi[2][ATK][20];
    __shared__ __align__(16) unsigned short Klo[2][ATK][20];
    __shared__ __align__(16) unsigned short Vhi[2][16][72];
    __shared__ __align__(16) unsigned short Vlo[2][16][72];

    int h = blockIdx.x, b = blockIdx.y, qt = blockIdx.z;
    int t = threadIdx.x;
    int w = t >> 6, lane = t & 63;
    int r16 = lane & 15, g = lane >> 4;

    int qbase[2];
    qbase[0] = qt * ATQ + w * 16;
    qbase[1] = qt * ATQ + 64 + w * 16;
    bshort4 qh[2], ql[2];
    const float* mrow[2] = {nullptr, nullptr};
    #pragma unroll
    for (int i = 0; i < 2; i++) {
        int qg = qbase[i] + r16;
        int qc = qg < Nq ? qg : Nq - 1;
        float4 qv = *((const float4*)(Q + ((size_t)(b * Nq + qc)) * EE + h * 16 + 4 * g));
        float qa[4] = {qv.x, qv.y, qv.z, qv.w};
        #pragma unroll
        for (int j = 0; j < 4; j++) {
            unsigned short hh = f2b(qa[j]);
            qh[i][j] = (short)hh;
            ql[i][j] = (short)f2b(qa[j] - b2f_(hh));
        }
        if (mask) mrow[i] = mask + ((size_t)(b * Nq + qc)) * Nk;
    }

    floatx4 o_acc[2];
    o_acc[0] = (floatx4){0.0f, 0.0f, 0.0f, 0.0f};
    o_acc[1] = (floatx4){0.0f, 0.0f, 0.0f, 0.0f};
    float m_i[2] = {-1e30f, -1e30f};
    float l_i[2] = {0.0f, 0.0f};

    int skr = t >> 2;
    int sc  = (t & 3) * 4;
    const float* Kbase = K + ((size_t)b * Nk) * EE + h * 16 + sc;
    const float* Vbase = V + ((size_t)b * Nk) * EE + h * 16 + sc;

    {
        int krc = skr < Nk ? skr : Nk - 1;
        float4 kv = *((const float4*)(Kbase + (size_t)krc * EE));
        float4 vv = *((const float4*)(Vbase + (size_t)krc * EE));
        float ka[4] = {kv.x, kv.y, kv.z, kv.w};
        float va[4] = {vv.x, vv.y, vv.z, vv.w};
        bshort4 khv, klv;
        #pragma unroll
        for (int j = 0; j < 4; j++) {
            unsigned short hh = f2b(ka[j]);
            khv[j] = (short)hh;
            klv[j] = (short)f2b(ka[j] - b2f_(hh));
        }
        *((bshort4*)&Khi[0][skr][sc]) = khv;
        *((bshort4*)&Klo[0][skr][sc]) = klv;
        #pragma unroll
        for (int j = 0; j < 4; j++) {
            unsigned short hh = f2b(va[j]);
            Vhi[0][sc + j][skr] = hh;
            Vlo[0][sc + j][skr] = (unsigned short)f2b(va[j] - b2f_(hh));
        }
    }
    __syncthreads();

    int nkt = (Nk + ATK - 1) / ATK;
    for (int kt = 0; kt < nkt; kt++) {
        int cur = kt & 1;
        int k0 = kt * ATK;

        float4 nkv, nvv;
        bool pf = (kt + 1 < nkt);
        if (pf) {
            int kr = k0 + ATK + skr;
            int krc = kr < Nk ? kr : Nk - 1;
            nkv = *((const float4*)(Kbase + (size_t)krc * EE));
            nvv = *((const float4*)(Vbase + (size_t)krc * EE));
        }

        float p[2][4][4];
        #pragma unroll
        for (int s = 0; s < 4; s++) {
            bshort4 kh = *((const bshort4*)&Khi[cur][s * 16 + r16][4 * g]);
            bshort4 kl = *((const bshort4*)&Klo[cur][s * 16 + r16][4 * g]);
            #pragma unroll
            for (int i = 0; i < 2; i++) {
                floatx4 acc = (floatx4){0.0f, 0.0f, 0.0f, 0.0f};
                acc = __builtin_amdgcn_mfma_f32_16x16x16bf16_1k(kh, qh[i], acc, 0, 0, 0);
                acc = __builtin_amdgcn_mfma_f32_16x16x16bf16_1k(kh, ql[i], acc, 0, 0, 0);
                acc = __builtin_amdgcn_mfma_f32_16x16x16bf16_1k(kl, qh[i], acc, 0, 0, 0);
                #pragma unroll
                for (int r = 0; r < 4; r++) p[i][s][r] = acc[r];
            }
        }

        #pragma unroll
        for (int i = 0; i < 2; i++)
            #pragma unroll
            for (int s = 0; s < 4; s++)
                #pragma unroll
                for (int r = 0; r < 4; r++) {
                    int kc = k0 + s * 16 + 4 * g + r;
                    p[i][s][r] = (kc < Nk) ? p[i][s][r] * 0.25f : -1e30f;
                }
        if (mask) {
            #pragma unroll
            for (int i = 0; i < 2; i++) {
                #pragma unroll
                for (int s = 0; s < 4; s++) {
                    int c0 = k0 + s * 16 + 4 * g;
                    float mv[4];
                    if (c0 + 3 < Nk) {
                        float4 m4 = *((const float4*)(mrow[i] + c0));
                        mv[0] = m4.x; mv[1] = m4.y; mv[2] = m4.z; mv[3] = m4.w;
                    } else {
                        #pragma unroll
                        for (int r = 0; r < 4; r++)
                            mv[r] = (c0 + r < Nk) ? mrow[i][c0 + r] : 0.0f;
                    }
                    #pragma unroll
                    for (int r = 0; r < 4; r++) p[i][s][r] += mv[r];
                }
            }
        }

        #pragma unroll
        for (int i = 0; i < 2; i++) {
            float tmax = -1e30f;
            #pragma unroll
            for (int s = 0; s < 4; s++)
                #pragma unroll
                for (int r = 0; r < 4; r++) tmax = fmaxf(tmax, p[i][s][r]);
            tmax = fmaxf(tmax, __shfl_xor(tmax, 16));
            tmax = fmaxf(tmax, __shfl_xor(tmax, 32));
            float m_new = fmaxf(m_i[i], tmax);
            float alpha = __expf(m_i[i] - m_new);
            float lloc = 0.0f;
            #pragma unroll
            for (int s = 0; s < 4; s++) {
                #pragma unroll
                for (int r = 0; r < 4; r++) {
                    float e = __expf(p[i][s][r] - m_new);
                    p[i][s][r] = e; lloc += e;
                }
            }
            lloc += __shfl_xor(lloc, 16);
            lloc += __shfl_xor(lloc, 32);
            l_i[i] = l_i[i] * alpha + lloc;
            m_i[i] = m_new;
            #pragma unroll
            for (int r = 0; r < 4; r++) {
                float ar = __shfl(alpha, 4 * g + r);
                o_acc[i][r] *= ar;
            }
        }

        #pragma unroll
        for (int s = 0; s < 4; s++) {
            bshort4 vh = *((const bshort4*)&Vhi[cur][r16][s * 16 + 4 * g]);
            bshort4 vl = *((const bshort4*)&Vlo[cur][r16][s * 16 + 4 * g]);
            #pragma unroll
            for (int i = 0; i < 2; i++) {
                bshort4 ph, pl;
                #pragma unroll
                for (int r = 0; r < 4; r++) {
                    unsigned short hh = f2b(p[i][s][r]);
                    ph[r] = (short)hh;
                    pl[r] = (short)f2b(p[i][s][r] - b2f_(hh));
                }
                o_acc[i] = __builtin_amdgcn_mfma_f32_16x16x16bf16_1k(ph, vh, o_acc[i], 0, 0, 0);
                o_acc[i] = __builtin_amdgcn_mfma_f32_16x16x16bf16_1k(ph, vl, o_acc[i], 0, 0, 0);
                o_acc[i] = __builtin_amdgcn_mfma_f32_16x16x16bf16_1k(pl, vh, o_acc[i], 0, 0, 0);
            }
        }

        if (pf) {
            int nb = cur ^ 1;
            float ka[4] = {nkv.x, nkv.y, nkv.z, nkv.w};
            float va[4] = {nvv.x, nvv.y, nvv.z, nvv.w};
            bshort4 khv, klv;
            #pragma unroll
            for (int j = 0; j < 4; j++) {
                unsigned short hh = f2b(ka[j]);
                khv[j] = (short)hh;
                klv[j] = (short)f2b(ka[j] - b2f_(hh));
            }
            *((bshort4*)&Khi[nb][skr][sc]) = khv;
            *((bshort4*)&Klo[nb][skr][sc]) = klv;
            #pragma unroll
            for (int j = 0; j < 4; j++) {
                unsigned short hh = f2b(va[j]);
                Vhi[nb][sc + j][skr] = hh;
                Vlo[nb][sc + j][skr] = (unsigned short)f2b(va[j] - b2f_(hh));
            }
        }
        __syncthreads();
    }

    #pragma unroll
    for (int i = 0; i < 2; i++) {
        #pragma unroll
        for (int r = 0; r < 4; r++) {
            float lr = __shfl(l_i[i], 4 * g + r);
            int qrow = qbase[i] + 4 * g + r;
            if (qrow < Nq)
                O[((size_t)(b * Nq + qrow)) * EE + h * 16 + r16] = o_acc[i][r] / lr;
        }
    }
}

// ---------------- InstanceNorm over node axis ----------------
__global__ __launch_bounds__(64) void inorm_k(
    const float* __restrict__ X, const float* __restrict__ Y,
    const float* __restrict__ g, const float* __restrict__ bb,
    float* __restrict__ Out)
{
    int be = blockIdx.x;
    int b = be >> 7, e = be & 127;
    int t = threadIdx.x;
    float vals[9];
    float s = 0.0f, s2 = 0.0f;
    int c = 0;
    for (int n = t; n < NN; n += 64) {
        size_t off = ((size_t)(b * NN + n)) * EE + e;
        float v = X[off] + Y[off];
        vals[c++] = v; s += v; s2 += v * v;
    }
    #pragma unroll
    for (int o = 32; o > 0; o >>= 1) { s += __shfl_down(s, o); s2 += __shfl_down(s2, o); }
    s = __shfl(s, 0); s2 = __shfl(s2, 0);
    float mu = s * (1.0f / NN);
    float var = s2 * (1.0f / NN) - mu * mu;
    float inv = rsqrtf(var + 1e-5f);
    float gg = g[e], bv = bb[e];
    c = 0;
    for (int n = t; n < NN; n += 64) {
        size_t off = ((size_t)(b * NN + n)) * EE + e;
        Out[off] = (vals[c++] - mu) * inv * gg + bv;
    }
}

__global__ void zero_k(float* p, int n) {
    int i = blockIdx.x * 256 + threadIdx.x;
    if (i < n) p[i] = 0.0f;
}

__global__ __launch_bounds__(128) void encsum_k(const float* __restrict__ enc, float* __restrict__ esum) {
    int b = blockIdx.x, ch = blockIdx.y, t = threadIdx.x;
    float a = 0.0f;
    for (int i = 0; i < 65; i++) {
        int n = ch * 65 + i;
        a += enc[((size_t)(b * NN + n)) * EE + t];
    }
    atomicAdd(&esum[b * EE + t], a);
}

// mt[b,e] = sum_f (esum[b,f]/N) * Wr[e, 128+f]
__global__ __launch_bounds__(128) void meanterm_k(
    const float* __restrict__ esum, const float* __restrict__ Wr, float* __restrict__ mt)
{
    int b = blockIdx.x, t = threadIdx.x;
    __shared__ float em[128];
    em[t] = esum[b * EE + t] * (1.0f / NN);
    __syncthreads();
    const float* w = Wr + (size_t)t * 257 + 128;
    float a = 0.0f;
    for (int f = 0; f < 128; f++) a += em[f] * w[f];
    mt[b * EE + t] = a;
}

__global__ __launch_bounds__(128) void subtour_k(
    const float* __restrict__ enc, const int* __restrict__ subn,
    const int* __restrict__ subl, float* __restrict__ subm)
{
    int bm = blockIdx.x;
    int b = bm / MM;
    int t = threadIdx.x;
    int len = subl[bm];
    float acc = 0.0f; int cnt = 0;
    for (int l = 0; l < LL; l++) {
        int node = subn[(size_t)bm * LL + l];
        if (l < len && node >= DEPOT_) {
            acc += enc[((size_t)(b * NN + node)) * EE + t];
            cnt++;
        }
    }
    float cf = (float)(cnt < 1 ? 1 : cnt);
    subm[(size_t)bm * EE + t] = acc / cf;
}

// ---------------- decoder q: gather/blend of precomputed GEMM outputs ----------------
// R  = enc @ Wqr[:, :128]^T   (routing, minus mean/load terms)
// L1 = enc @ Wql[:, :128]^T   (location, last_emb part)
// SM2= subm @ Wql[:,128:]^T   (location, sub_mean part)
__global__ __launch_bounds__(128) void decq_gather_k(
    const float* __restrict__ R, const float* __restrict__ L1, const float* __restrict__ SM2,
    const float* __restrict__ mterm, const int* __restrict__ cur,
    const float* __restrict__ loadv, const int* __restrict__ sel,
    const float* __restrict__ Wqr, float* __restrict__ out)
{
    int bm = blockIdx.x;
    int b = bm / MM;
    int t = threadIdx.x;
    int cn = cur[bm];
    int s2v = sel[(size_t)bm * 4 + 2];
    bool flag = (s2v >= DEPOT_) && (cn < DEPOT_);
    size_t eo = ((size_t)(b * NN + cn)) * EE + t;
    float q;
    if (flag) q = L1[eo] + SM2[(size_t)bm * EE + t];
    else      q = R[eo] + mterm[b * EE + t] + loadv[bm] * Wqr[(size_t)t * 257 + 256];
    out[(size_t)bm * EE + t] = q;
}

extern "C" void kernel_launch(void* const* d_in, const int* in_sizes, int n_in,
                              void* d_out, int out_size, void* d_ws, size_t ws_size,
                              hipStream_t stream)
{
    const float* depot = (const float*)d_in[0];
    const float* cust  = (const float*)d_in[1];
    const float* mask  = (const float*)d_in[2];
    const float* loadv = (const float*)d_in[3];
    const int*  cur   = (const int*)d_in[4];
    const int*  subn  = (const int*)d_in[5];
    const int*  subl  = (const int*)d_in[6];
    const int*  sel   = (const int*)d_in[7];
    const float* Wdep  = (const float*)d_in[8];
    const float* bdep  = (const float*)d_in[9];
    const float* Wcus  = (const float*)d_in[10];
    const float* bcus  = (const float*)d_in[11];
    const float* Wq    = (const float*)d_in[12];
    const float* Wk    = (const float*)d_in[13];
    const float* Wv    = (const float*)d_in[14];
    const float* Wc    = (const float*)d_in[15];
    const float* Wcb   = (const float*)d_in[16];
    const float* n1g   = (const float*)d_in[17];
    const float* n1b   = (const float*)d_in[18];
    const float* fW1   = (const float*)d_in[19];
    const float* fb1   = (const float*)d_in[20];
    const float* fW2   = (const float*)d_in[21];
    const float* fb2   = (const float*)d_in[22];
    const float* n2g   = (const float*)d_in[23];
    const float* n2b   = (const float*)d_in[24];
    const float* Wql   = (const float*)d_in[25];
    const float* Wqr   = (const float*)d_in[26];
    const float* dWk   = (const float*)d_in[27];
    const float* dWv   = (const float*)d_in[28];
    const float* dWc   = (const float*)d_in[29];
    const float* dWcb  = (const float*)d_in[30];

    const size_t SZ = (size_t)BB * NN * EE;           // 2,129,920
    float* f0 = (float*)d_ws;       // x / encoded
    float* f1 = f0 + SZ;            // q / k_d / logits (spans f1..f5)
    float* f2 = f1 + SZ;            // k / v_d
    float* f3 = f2 + SZ;            // v / encsum + meanterm
    float* f4 = f3 + SZ;            // mh,ff2 out / sub_mean, dec attn
    float* f5 = f4 + SZ;            // x1 / final_q
    float* big = f5 + SZ;           // ffh (B*N*FFH) / R,L1,SM2 / dec score
    unsigned short* WHp = (unsigned short*)(big + (size_t)BB * NN * FFH_);
    unsigned short* WLp = WHp + WTOT;

    dim3 g4(EE / 64, (BB * NN) / 128);     // (2, 130)
    dim3 g16(FFH_ / 64, (BB * NN) / 128);  // (8, 130)
    dim3 gq3(6, (BB * NN) / 128);          // fused QKV
    dim3 gq2(4, (BB * NN) / 128);          // fused 2-way
    dim3 gmha(HH, BB, (NN + ATQ - 1) / ATQ);  // (8, 32, 5)
    dim3 gsc((NN + GT - 1) / GT, (NN + GT - 1) / GT, BB);  // (9, 9, 32)

    wconv_k<<<(WTOT + 255) / 256, 256, 0, stream>>>(Wq, Wk, Wv, Wc, fW1, fW2,
                                                    dWk, dWv, dWc, Wql, Wqr, WHp, WLp);
    embed_k<<<(BB * NN * EE) / 256, 256, 0, stream>>>(depot, cust, Wdep, bdep, Wcus, bcus, f0);

    for (int i = 0; i < NL_; i++) {
        const unsigned short* lH = WHp + (size_t)i * WLS;
        const unsigned short* lL = WLp + (size_t)i * WLS;
        gemm_qkv3_k<<<gq3, 256, 0, stream>>>(f0, EE, lH, lL, EE, f1, f2, f3, EE, EE);
        fmha16_k<<<gmha, 256, 0, stream>>>(f1, f2, f3, nullptr, f4, NN, NN);
        gemm_pc_k<<<g4, 256, 0, stream>>>(f4, EE, lH + 49152, lL + 49152, EE, Wcb + i * EE, f1, EE, EE, 0);
        inorm_k<<<BB * EE, 64, 0, stream>>>(f0, f1, n1g + i * EE, n1b + i * EE, f5);
        gemm_pc_k<<<g16, 256, 0, stream>>>(f5, EE, lH + 65536, lL + 65536, EE, fb1 + i * FFH_, big, FFH_, EE, 1);
        gemm_pc_k<<<g4, 256, 0, stream>>>(big, FFH_, lH + 131072, lL + 131072, FFH_, fb2 + i * EE, f1, EE, FFH_, 0);
        inorm_k<<<BB * EE, 64, 0, stream>>>(f5, f1, n2g + i * EE, n2b + i * EE, f0);
    }

    // ---- decoder ----
    const unsigned short* dH = WHp + WDEC;
    const unsigned short* dL = WLp + WDEC;
    gemm_qkv3_k<<<gq2, 256, 0, stream>>>(f0, EE, dH, dL, EE, f1, f2, f2, EE, EE);  // k_d, v_d

    zero_k<<<(BB * EE + 255) / 256, 256, 0, stream>>>(f3, BB * EE);
    encsum_k<<<dim3(BB, 8), 128, 0, stream>>>(f0, f3);
    meanterm_k<<<BB, 128, 0, stream>>>(f3, Wqr, f3 + BB * EE);
    subtour_k<<<BB * MM, 128, 0, stream>>>(f0, subn, subl, f4);

    // R (big), L1 (big+SZ) from encoded; SM2 (big+2SZ) from subm
    gemm_qkv3_k<<<gq2, 256, 0, stream>>>(f0, EE, dH + 49152, dL + 49152, EE, big, big + SZ, big + SZ, EE, EE);
    gemm_pc_k<<<g4, 256, 0, stream>>>(f4, EE, dH + 49152 + 32768, dL + 49152 + 32768, EE, nullptr, big + 2 * SZ, EE, EE, 0);
    decq_gather_k<<<BB * MM, 128, 0, stream>>>(big, big + SZ, big + 2 * SZ, f3 + BB * EE, cur, loadv, sel, Wqr, f5);

    fmha16_k<<<gmha, 256, 0, stream>>>(f5, f1, f2, mask, f4, MM, NN);
    gemm_pc_k<<<g4, 256, 0, stream>>>(f4, EE, dH + 32768, dL + 32768, EE, dWcb, big, EE, EE, 0);

    // logits (B x 520 x 520) at f1 (spans f1..f5; all dead now)
    sgemm_k<<<gsc, 256, 0, stream>>>(big, f0, f1);
    smax_k<<<BB * MM, 64, 0, stream>>>(f1, mask, (float*)d_out);
}